// Round 4
// baseline (338.527 us; speedup 1.0000x reference)
//
#include <hip/hip_runtime.h>
#include <hip/hip_bf16.h>
#include <stdint.h>

typedef short bf16x8 __attribute__((ext_vector_type(8)));
typedef float f32x4 __attribute__((ext_vector_type(4)));

__device__ __forceinline__ unsigned short f2bf(float f) {
  union { float f; unsigned int u; } v;
  v.f = f;
  unsigned int u = v.u;
  u = (u + 0x7fffu + ((u >> 16) & 1u)) >> 16;  // RNE
  return (unsigned short)u;
}

__device__ __forceinline__ float asf(unsigned int u) {
  union { unsigned int u; float f; } v; v.u = u; return v.f;
}

__device__ __forceinline__ unsigned int pack_bf16(float x, float y) {
  return (unsigned int)f2bf(x) | ((unsigned int)f2bf(y) << 16);
}

typedef union { bf16x8 v; unsigned int u[4]; } frag_u;

// global->LDS async copy, 16B per lane. LDS dest = wave-uniform base + lane*16.
__device__ __forceinline__ void gload16(const void* g, void* lds) {
  __builtin_amdgcn_global_load_lds(
      (const __attribute__((address_space(1))) unsigned int*)(unsigned long long)g,
      (__attribute__((address_space(3))) unsigned int*)(unsigned long long)(unsigned)(unsigned long long)lds,
      16, 0, 0);
}

// Read a bf16x8 fragment from a 64x64 tile whose 16B chunks are XOR-swizzled:
// chunk j of row r stored at position j ^ (r&7).
__device__ __forceinline__ bf16x8 lds_frag(const unsigned short* t, int row, int ch4q) {
  return *(const bf16x8*)(t + row * 64 + ((ch4q ^ (row & 7)) << 3));
}

// ---------------------------------------------------------------------------
// Kernel 1: prep — x -> bf16, 7 weights -> transposed bf16 (Wt[n][k] = W[k][n])
// ---------------------------------------------------------------------------
__global__ __launch_bounds__(256) void prep_kernel(
    const float* __restrict__ x,
    const float* __restrict__ Wq, const float* __restrict__ Wk, const float* __restrict__ Wv,
    const float* __restrict__ Wfh, const float* __restrict__ Wfg,
    const float* __restrict__ Wrh, const float* __restrict__ Wrg,
    unsigned short* __restrict__ xb, unsigned short* __restrict__ wt) {
  int bid = blockIdx.x;
  int tid = threadIdx.x;
  if (bid < 448) {
    __shared__ float tile[64][65];
    int mat = bid >> 6;
    int t = bid & 63;
    int tr = (t >> 3) * 64, tc = (t & 7) * 64;
    const float* W = (mat == 0) ? Wq : (mat == 1) ? Wk : (mat == 2) ? Wv
                   : (mat == 3) ? Wfh : (mat == 4) ? Wfg : (mat == 5) ? Wrh : Wrg;
    unsigned short* Wt = wt + (size_t)mat * 512 * 512;
    for (int rep = 0; rep < 16; rep++) {
      int idx = rep * 256 + tid;
      int r = idx >> 6, c = idx & 63;
      tile[r][c] = W[(tr + r) * 512 + tc + c];
    }
    __syncthreads();
    for (int rep = 0; rep < 16; rep++) {
      int idx = rep * 256 + tid;
      int r = idx >> 6, c = idx & 63;
      Wt[(tc + r) * 512 + tr + c] = f2bf(tile[c][r]);
    }
  } else {
    int blk = bid - 448;
    const float4* xi = (const float4*)x;
    for (int rep = 0; rep < 32; rep++) {
      int i = blk * 256 + tid + rep * 16384;
      float4 v = xi[i];
      unsigned int lo = (unsigned int)f2bf(v.x) | ((unsigned int)f2bf(v.y) << 16);
      unsigned int hi = (unsigned int)f2bf(v.z) | ((unsigned int)f2bf(v.w) << 16);
      uint2 u; u.x = lo; u.y = hi;
      *(uint2*)&xb[(size_t)i * 4] = u;
    }
  }
}

// ---------------------------------------------------------------------------
// Kernel 2: QKV projection, LDS-staged GEMM. grid (8 nb, 64 mt): XCD = nb,
// so each XCD keeps its 3 weight panels L2-resident; block's n-range = one
// head for V. Epilogue stages Q/K (row-major) and V (transposed) in LDS and
// writes full 128B lines.
// ---------------------------------------------------------------------------
__global__ __launch_bounds__(256, 2) void qkv_kernel(
    const unsigned short* __restrict__ xb,
    const unsigned short* __restrict__ wtq, const unsigned short* __restrict__ wtk,
    const unsigned short* __restrict__ wtv,
    const float* __restrict__ bq, const float* __restrict__ bk, const float* __restrict__ bv,
    unsigned short* __restrict__ Qb, unsigned short* __restrict__ Kb,
    unsigned short* __restrict__ Vtb) {
  __shared__ unsigned short As[64 * 64];
  __shared__ unsigned short Bq[64 * 64];
  __shared__ unsigned short Bk[64 * 64];
  __shared__ unsigned short Bv[64 * 64];
  __shared__ __attribute__((aligned(16))) unsigned short st[3][64 * 72];
  const int m0 = blockIdx.y * 64, n0 = blockIdx.x * 64;
  const int tid = threadIdx.x, w = tid >> 6, lane = tid & 63;
  const int c = lane & 15, quad = lane >> 4;
  const int wm = w & 1, wn = w >> 1;
  const int rsel = lane >> 3, csel = lane & 7;
  const int sc = csel ^ rsel;  // stage swizzle (row&7 == rsel here)
  const char* Ag  = (const char*)xb  + (size_t)(m0 + w * 16 + rsel) * 1024 + sc * 16;
  const char* Bgq = (const char*)wtq + (size_t)(n0 + w * 16 + rsel) * 1024 + sc * 16;
  const char* Bgk = (const char*)wtk + (size_t)(n0 + w * 16 + rsel) * 1024 + sc * 16;
  const char* Bgv = (const char*)wtv + (size_t)(n0 + w * 16 + rsel) * 1024 + sc * 16;
  unsigned short* lA = &As[w * 1024];
  unsigned short* lQ = &Bq[w * 1024];
  unsigned short* lK = &Bk[w * 1024];
  unsigned short* lV = &Bv[w * 1024];

  f32x4 acc[3][2][2];
  f32x4 z4 = {0.f, 0.f, 0.f, 0.f};
#pragma unroll
  for (int o = 0; o < 3; o++)
#pragma unroll
    for (int i = 0; i < 2; i++)
#pragma unroll
      for (int j = 0; j < 2; j++) acc[o][i][j] = z4;

  for (int ks = 0; ks < 8; ks++) {
    if (ks) __syncthreads();
    const int kb = ks * 128;
    gload16(Ag + kb, lA);        gload16(Ag + kb + 8192, lA + 512);
    gload16(Bgq + kb, lQ);       gload16(Bgq + kb + 8192, lQ + 512);
    gload16(Bgk + kb, lK);       gload16(Bgk + kb + 8192, lK + 512);
    gload16(Bgv + kb, lV);       gload16(Bgv + kb + 8192, lV + 512);
    __syncthreads();
#pragma unroll
    for (int ch = 0; ch < 2; ch++) {
      const int cq = ch * 4 + quad;
      bf16x8 a0 = lds_frag(As, wm * 32 + c, cq);
      bf16x8 a1 = lds_frag(As, wm * 32 + 16 + c, cq);
#pragma unroll
      for (int nt = 0; nt < 2; nt++) {
        const int rb = wn * 32 + nt * 16 + c;
        bf16x8 fq = lds_frag(Bq, rb, cq);
        bf16x8 fk = lds_frag(Bk, rb, cq);
        bf16x8 fv = lds_frag(Bv, rb, cq);
        acc[0][0][nt] = __builtin_amdgcn_mfma_f32_16x16x32_bf16(a0, fq, acc[0][0][nt], 0, 0, 0);
        acc[0][1][nt] = __builtin_amdgcn_mfma_f32_16x16x32_bf16(a1, fq, acc[0][1][nt], 0, 0, 0);
        acc[1][0][nt] = __builtin_amdgcn_mfma_f32_16x16x32_bf16(a0, fk, acc[1][0][nt], 0, 0, 0);
        acc[1][1][nt] = __builtin_amdgcn_mfma_f32_16x16x32_bf16(a1, fk, acc[1][1][nt], 0, 0, 0);
        acc[2][0][nt] = __builtin_amdgcn_mfma_f32_16x16x32_bf16(a0, fv, acc[2][0][nt], 0, 0, 0);
        acc[2][1][nt] = __builtin_amdgcn_mfma_f32_16x16x32_bf16(a1, fv, acc[2][1][nt], 0, 0, 0);
      }
    }
  }

  // stage epilogue tiles: st[0]=Q rows t, st[1]=K rows t, st[2]=V rows d (transposed)
#pragma unroll
  for (int ms = 0; ms < 2; ms++)
#pragma unroll
    for (int nt = 0; nt < 2; nt++) {
      int n_l = wn * 32 + nt * 16 + c;
      int n = n0 + n_l;
      float biasq = bq[n], biask = bk[n], biasv = bv[n];
#pragma unroll
      for (int r = 0; r < 4; r++) {
        int m_l = wm * 32 + ms * 16 + quad * 4 + r;
        st[0][m_l * 72 + n_l] = f2bf((acc[0][ms][nt][r] + biasq) * 0.125f);
        st[1][m_l * 72 + n_l] = f2bf(acc[1][ms][nt][r] + biask);
        st[2][n_l * 72 + m_l] = f2bf(acc[2][ms][nt][r] + biasv);  // [d][t]
      }
    }
  __syncthreads();

  {
    const int row = tid >> 2, seg = tid & 3;
    const int h = n0 >> 6;                 // whole block = one head for V
    const int bb = m0 >> 10, tb0 = m0 & 1023;
    uint4 v0, v1;
    size_t g;
    v0 = *(uint4*)&st[0][row * 72 + seg * 16];
    v1 = *(uint4*)&st[0][row * 72 + seg * 16 + 8];
    g = (size_t)(m0 + row) * 512 + n0 + seg * 16;
    *(uint4*)&Qb[g] = v0; *(uint4*)&Qb[g + 8] = v1;
    v0 = *(uint4*)&st[1][row * 72 + seg * 16];
    v1 = *(uint4*)&st[1][row * 72 + seg * 16 + 8];
    *(uint4*)&Kb[g] = v0; *(uint4*)&Kb[g + 8] = v1;
    v0 = *(uint4*)&st[2][row * 72 + seg * 16];
    v1 = *(uint4*)&st[2][row * 72 + seg * 16 + 8];
    g = ((size_t)(bb * 8 + h) * 64 + row) * 1024 + tb0 + seg * 16;
    *(uint4*)&Vtb[g] = v0; *(uint4*)&Vtb[g + 8] = v1;
  }
}

// ---------------------------------------------------------------------------
// Kernel 3: zmask — grid (8 xcd, 32): batch pinned to 2 XCDs so K[b]+Q[b]
// (2MB) stays L2-resident. 8 waves split k. Mask bytes staged in LDS, then
// written as full 128B lines (kills the 28x write amplification).
// ---------------------------------------------------------------------------
__global__ __launch_bounds__(512, 2) void zmask_kernel(
    const unsigned short* __restrict__ Qb, const unsigned short* __restrict__ Kb,
    const float* __restrict__ conv_w, const float* __restrict__ conv_b,
    unsigned char* __restrict__ Mu8, float* __restrict__ invZg) {
  const int b = blockIdx.x >> 1;
  const int qt = (blockIdx.x & 1) * 32 + blockIdx.y;
  const int q0 = qt * 16;
  const int tid = threadIdx.x, w = tid >> 6, lane = tid & 63;
  const int c = lane & 15, quad = lane >> 4;

  __shared__ float zl[8][16];
  __shared__ __attribute__((aligned(16))) unsigned char mstage[16 * 1040];
  if (tid < 128) ((float*)zl)[tid] = 0.f;
  __syncthreads();

  f32x4 z4 = {0.f, 0.f, 0.f, 0.f};
  const size_t qrow = (size_t)(b * 1024 + q0 + c) * 512;
  bf16x8 qf[8][2];
#pragma unroll
  for (int h = 0; h < 8; h++) {
    qf[h][0] = *(const bf16x8*)&Qb[qrow + h * 64 + quad * 8];
    qf[h][1] = *(const bf16x8*)&Qb[qrow + h * 64 + 32 + quad * 8];
  }

  // pass 1: partial Z over this wave's 128 k
  float zp[8] = {0, 0, 0, 0, 0, 0, 0, 0};
  for (int kt = 0; kt < 8; kt++) {
    const int kk = w * 128 + kt * 16;
    const size_t krow = (size_t)(b * 1024 + kk + c) * 512;
#pragma unroll
    for (int h = 0; h < 8; h++) {
      bf16x8 kf0 = *(const bf16x8*)&Kb[krow + h * 64 + quad * 8];
      bf16x8 kf1 = *(const bf16x8*)&Kb[krow + h * 64 + 32 + quad * 8];
      f32x4 s = __builtin_amdgcn_mfma_f32_16x16x32_bf16(kf0, qf[h][0], z4, 0, 0, 0);
      s = __builtin_amdgcn_mfma_f32_16x16x32_bf16(kf1, qf[h][1], s, 0, 0, 0);
      zp[h] += __expf(s[0]) + __expf(s[1]) + __expf(s[2]) + __expf(s[3]);
    }
  }
#pragma unroll
  for (int h = 0; h < 8; h++) {
    float z = zp[h];
    z += __shfl_xor(z, 16); z += __shfl_xor(z, 32);
    if (quad == 0) atomicAdd(&zl[h][c], z);
  }
  __syncthreads();

  float invZ[8];
#pragma unroll
  for (int h = 0; h < 8; h++) invZ[h] = 1.0f / zl[h][c];
  float cw[8];
#pragma unroll
  for (int h = 0; h < 8; h++) cw[h] = conv_w[h];
  const float cb = conv_b[0];

  // pass 2: gate -> mask bytes into LDS
  for (int kt = 0; kt < 8; kt++) {
    const int kk = w * 128 + kt * 16;
    const size_t krow = (size_t)(b * 1024 + kk + c) * 512;
    f32x4 zc = {cb, cb, cb, cb};
#pragma unroll
    for (int h = 0; h < 8; h++) {
      bf16x8 kf0 = *(const bf16x8*)&Kb[krow + h * 64 + quad * 8];
      bf16x8 kf1 = *(const bf16x8*)&Kb[krow + h * 64 + 32 + quad * 8];
      f32x4 s = __builtin_amdgcn_mfma_f32_16x16x32_bf16(kf0, qf[h][0], z4, 0, 0, 0);
      s = __builtin_amdgcn_mfma_f32_16x16x32_bf16(kf1, qf[h][1], s, 0, 0, 0);
#pragma unroll
      for (int r = 0; r < 4; r++) zc[r] += cw[h] * (__expf(s[r]) * invZ[h]);
    }
    unsigned int packed = 0;
#pragma unroll
    for (int r = 0; r < 4; r++) {
      unsigned int m = (zc[r] <= 0.f ? 1u : 0u) | (zc[r] >= 0.f ? 2u : 0u);
      packed |= m << (8 * r);
    }
    *(unsigned int*)&mstage[c * 1040 + kk + quad * 4] = packed;
  }
  if (tid < 128) {
    int hh = tid >> 4, qq = tid & 15;
    invZg[(size_t)(b * 8 + hh) * 1024 + q0 + qq] = 1.0f / zl[hh][qq];
  }
  __syncthreads();
  {
    const int row = tid >> 5, off = (tid & 31) * 32;
    uint4 a0 = *(uint4*)&mstage[row * 1040 + off];
    uint4 a1 = *(uint4*)&mstage[row * 1040 + off + 16];
    size_t g = (size_t)(b * 1024 + q0 + row) * 1024 + off;
    *(uint4*)&Mu8[g] = a0; *(uint4*)&Mu8[g + 16] = a1;
  }
}

// ---------------------------------------------------------------------------
// Kernel 4: pv — grid (8 h, 64): head pinned to XCD (K/V slices L2-resident).
// Barrier-free main loop; LDS-staged coalesced Tf/Tr writes.
// ---------------------------------------------------------------------------
__global__ __launch_bounds__(256, 2) void pv_kernel(
    const unsigned short* __restrict__ Qb, const unsigned short* __restrict__ Kb,
    const unsigned short* __restrict__ Vtb,
    const unsigned char* __restrict__ Mu8, const float* __restrict__ invZg,
    unsigned short* __restrict__ Tfb, unsigned short* __restrict__ Trb) {
  const int h = blockIdx.x;
  const int b = blockIdx.y >> 4, qt = blockIdx.y & 15;
  const int tid = threadIdx.x, w = tid >> 6, lane = tid & 63;
  const int c = lane & 15, quad = lane >> 4;
  const int q = qt * 64 + w * 16 + c;

  __shared__ __attribute__((aligned(16))) unsigned short tsf[64 * 72];
  __shared__ __attribute__((aligned(16))) unsigned short tsr[64 * 72];

  f32x4 z4 = {0.f, 0.f, 0.f, 0.f};
  const size_t qrow = (size_t)(b * 1024 + q) * 512 + h * 64;
  bf16x8 qf0 = *(const bf16x8*)&Qb[qrow + quad * 8];
  bf16x8 qf1 = *(const bf16x8*)&Qb[qrow + 32 + quad * 8];
  const float invZ = invZg[(size_t)(b * 8 + h) * 1024 + q];
  const size_t mrow = (size_t)(b * 1024 + q) * 1024;
  const size_t vbase = ((size_t)(b * 8 + h) * 64 + c) * 1024;

  f32x4 accf[4], accr[4];
#pragma unroll
  for (int i = 0; i < 4; i++) { accf[i] = z4; accr[i] = z4; }
  float zf = 0.f, zr = 0.f;

  for (int kt = 0; kt < 64; kt++) {
    const int k0 = kt * 16;
    const size_t krow = (size_t)(b * 1024 + k0 + c) * 512 + h * 64;
    bf16x8 kf0 = *(const bf16x8*)&Kb[krow + quad * 8];
    bf16x8 kf1 = *(const bf16x8*)&Kb[krow + 32 + quad * 8];
    f32x4 s = __builtin_amdgcn_mfma_f32_16x16x32_bf16(kf0, qf0, z4, 0, 0, 0);
    s = __builtin_amdgcn_mfma_f32_16x16x32_bf16(kf1, qf1, s, 0, 0, 0);
    const unsigned int mb = *(const unsigned int*)&Mu8[mrow + k0 + quad * 4];
    float ea[4];
#pragma unroll
    for (int r = 0; r < 4; r++) ea[r] = __expf(__expf(s[r]) * invZ);
    frag_u pF, pR;
    pF.u[0] = pack_bf16((mb & 0x1u) ? ea[0] : 1.f, (mb & 0x100u) ? ea[1] : 1.f);
    pF.u[1] = pack_bf16((mb & 0x10000u) ? ea[2] : 1.f, (mb & 0x1000000u) ? ea[3] : 1.f);
    pF.u[2] = 0; pF.u[3] = 0;
    pR.u[0] = pack_bf16((mb & 0x2u) ? ea[0] : 1.f, (mb & 0x200u) ? ea[1] : 1.f);
    pR.u[1] = pack_bf16((mb & 0x20000u) ? ea[2] : 1.f, (mb & 0x2000000u) ? ea[3] : 1.f);
    pR.u[2] = 0; pR.u[3] = 0;
    zf += asf(pF.u[0] << 16) + asf(pF.u[0] & 0xffff0000u)
        + asf(pF.u[1] << 16) + asf(pF.u[1] & 0xffff0000u);
    zr += asf(pR.u[0] << 16) + asf(pR.u[0] & 0xffff0000u)
        + asf(pR.u[1] << 16) + asf(pR.u[1] & 0xffff0000u);
#pragma unroll
    for (int dm = 0; dm < 4; dm++) {
      frag_u vf;
      uint2 vv = *(const uint2*)&Vtb[vbase + (size_t)dm * 16 * 1024 + k0 + quad * 4];
      vf.u[0] = vv.x; vf.u[1] = vv.y; vf.u[2] = 0; vf.u[3] = 0;
      accf[dm] = __builtin_amdgcn_mfma_f32_16x16x32_bf16(vf.v, pF.v, accf[dm], 0, 0, 0);
      accr[dm] = __builtin_amdgcn_mfma_f32_16x16x32_bf16(vf.v, pR.v, accr[dm], 0, 0, 0);
    }
  }

  zf += __shfl_xor(zf, 16); zf += __shfl_xor(zf, 32);
  zr += __shfl_xor(zr, 16); zr += __shfl_xor(zr, 32);
  const float izf = 1.0f / zf, izr = 1.0f / zr;
  const int qrow_l = w * 16 + c;
#pragma unroll
  for (int dm = 0; dm < 4; dm++) {
    uint2 u;
    u.x = pack_bf16(accf[dm][0] * izf, accf[dm][1] * izf);
    u.y = pack_bf16(accf[dm][2] * izf, accf[dm][3] * izf);
    *(uint2*)&tsf[qrow_l * 72 + dm * 16 + quad * 4] = u;
    u.x = pack_bf16(accr[dm][0] * izr, accr[dm][1] * izr);
    u.y = pack_bf16(accr[dm][2] * izr, accr[dm][3] * izr);
    *(uint2*)&tsr[qrow_l * 72 + dm * 16 + quad * 4] = u;
  }
  __syncthreads();
  {
    const int row = tid >> 2, seg = tid & 3;
    const size_t g = (size_t)(b * 1024 + qt * 64 + row) * 512 + h * 64 + seg * 16;
    uint4 a0 = *(uint4*)&tsf[row * 72 + seg * 16];
    uint4 a1 = *(uint4*)&tsf[row * 72 + seg * 16 + 8];
    *(uint4*)&Tfb[g] = a0; *(uint4*)&Tfb[g + 8] = a1;
    a0 = *(uint4*)&tsr[row * 72 + seg * 16];
    a1 = *(uint4*)&tsr[row * 72 + seg * 16 + 8];
    *(uint4*)&Trb[g] = a0; *(uint4*)&Trb[g + 8] = a1;
  }
}

// ---------------------------------------------------------------------------
// Kernel 5: final — LDS-staged fused 4-GEMM + gate combine. grid (8 nb, 64 mt).
// ---------------------------------------------------------------------------
__global__ __launch_bounds__(256, 2) void final_kernel(
    const unsigned short* __restrict__ Tfb, const unsigned short* __restrict__ Trb,
    const unsigned short* __restrict__ wfh, const unsigned short* __restrict__ wfg,
    const unsigned short* __restrict__ wrh, const unsigned short* __restrict__ wrg,
    const float* __restrict__ bfh, const float* __restrict__ bfg,
    const float* __restrict__ brh, const float* __restrict__ brg,
    float* __restrict__ out) {
  __shared__ unsigned short Atf[64 * 64];
  __shared__ unsigned short Atr[64 * 64];
  __shared__ unsigned short Bfh[64 * 64];
  __shared__ unsigned short Bfg[64 * 64];
  __shared__ unsigned short Brh[64 * 64];
  __shared__ unsigned short Brg[64 * 64];
  const int m0 = blockIdx.y * 64, n0 = blockIdx.x * 64;
  const int tid = threadIdx.x, w = tid >> 6, lane = tid & 63;
  const int c = lane & 15, quad = lane >> 4;
  const int wm = w & 1, wn = w >> 1;
  const int rsel = lane >> 3, csel = lane & 7;
  const int sc = csel ^ rsel;
  const char* Agf = (const char*)Tfb + (size_t)(m0 + w * 16 + rsel) * 1024 + sc * 16;
  const char* Agr = (const char*)Trb + (size_t)(m0 + w * 16 + rsel) * 1024 + sc * 16;
  const char* Bg0 = (const char*)wfh + (size_t)(n0 + w * 16 + rsel) * 1024 + sc * 16;
  const char* Bg1 = (const char*)wfg + (size_t)(n0 + w * 16 + rsel) * 1024 + sc * 16;
  const char* Bg2 = (const char*)wrh + (size_t)(n0 + w * 16 + rsel) * 1024 + sc * 16;
  const char* Bg3 = (const char*)wrg + (size_t)(n0 + w * 16 + rsel) * 1024 + sc * 16;
  unsigned short* lAf = &Atf[w * 1024];
  unsigned short* lAr = &Atr[w * 1024];
  unsigned short* l0 = &Bfh[w * 1024];
  unsigned short* l1 = &Bfg[w * 1024];
  unsigned short* l2 = &Brh[w * 1024];
  unsigned short* l3 = &Brg[w * 1024];

  f32x4 acc[4][2][2];
  f32x4 z4 = {0.f, 0.f, 0.f, 0.f};
#pragma unroll
  for (int o = 0; o < 4; o++)
#pragma unroll
    for (int i = 0; i < 2; i++)
#pragma unroll
      for (int j = 0; j < 2; j++) acc[o][i][j] = z4;

  for (int ks = 0; ks < 8; ks++) {
    if (ks) __syncthreads();
    const int kb = ks * 128;
    gload16(Agf + kb, lAf);  gload16(Agf + kb + 8192, lAf + 512);
    gload16(Agr + kb, lAr);  gload16(Agr + kb + 8192, lAr + 512);
    gload16(Bg0 + kb, l0);   gload16(Bg0 + kb + 8192, l0 + 512);
    gload16(Bg1 + kb, l1);   gload16(Bg1 + kb + 8192, l1 + 512);
    gload16(Bg2 + kb, l2);   gload16(Bg2 + kb + 8192, l2 + 512);
    gload16(Bg3 + kb, l3);   gload16(Bg3 + kb + 8192, l3 + 512);
    __syncthreads();
#pragma unroll
    for (int ch = 0; ch < 2; ch++) {
      const int cq = ch * 4 + quad;
      bf16x8 af0 = lds_frag(Atf, wm * 32 + c, cq);
      bf16x8 af1 = lds_frag(Atf, wm * 32 + 16 + c, cq);
      bf16x8 ar0 = lds_frag(Atr, wm * 32 + c, cq);
      bf16x8 ar1 = lds_frag(Atr, wm * 32 + 16 + c, cq);
#pragma unroll
      for (int nt = 0; nt < 2; nt++) {
        const int rb = wn * 32 + nt * 16 + c;
        bf16x8 f0 = lds_frag(Bfh, rb, cq);
        bf16x8 f1 = lds_frag(Bfg, rb, cq);
        bf16x8 f2 = lds_frag(Brh, rb, cq);
        bf16x8 f3 = lds_frag(Brg, rb, cq);
        acc[0][0][nt] = __builtin_amdgcn_mfma_f32_16x16x32_bf16(af0, f0, acc[0][0][nt], 0, 0, 0);
        acc[0][1][nt] = __builtin_amdgcn_mfma_f32_16x16x32_bf16(af1, f0, acc[0][1][nt], 0, 0, 0);
        acc[1][0][nt] = __builtin_amdgcn_mfma_f32_16x16x32_bf16(af0, f1, acc[1][0][nt], 0, 0, 0);
        acc[1][1][nt] = __builtin_amdgcn_mfma_f32_16x16x32_bf16(af1, f1, acc[1][1][nt], 0, 0, 0);
        acc[2][0][nt] = __builtin_amdgcn_mfma_f32_16x16x32_bf16(ar0, f2, acc[2][0][nt], 0, 0, 0);
        acc[2][1][nt] = __builtin_amdgcn_mfma_f32_16x16x32_bf16(ar1, f2, acc[2][1][nt], 0, 0, 0);
        acc[3][0][nt] = __builtin_amdgcn_mfma_f32_16x16x32_bf16(ar0, f3, acc[3][0][nt], 0, 0, 0);
        acc[3][1][nt] = __builtin_amdgcn_mfma_f32_16x16x32_bf16(ar1, f3, acc[3][1][nt], 0, 0, 0);
      }
    }
  }

#pragma unroll
  for (int ms = 0; ms < 2; ms++)
#pragma unroll
    for (int nt = 0; nt < 2; nt++) {
      int n = n0 + wn * 32 + nt * 16 + c;
      float b0 = bfh[n], b1 = bfg[n], b2 = brh[n], b3 = brg[n];
      int t0 = m0 + wm * 32 + ms * 16 + quad * 4;
#pragma unroll
      for (int r = 0; r < 4; r++) {
        int t = t0 + r;
        float Ff = acc[0][ms][nt][r] + b0;
        float Gf = 1.0f / (1.0f + __expf(-(acc[1][ms][nt][r] + b1)));
        float Fr = acc[2][ms][nt][r] + b2;
        float Gr = 1.0f / (1.0f + __expf(-(acc[3][ms][nt][r] + b3)));
        float ef = __expf(Gf), er = __expf(Gr);
        out[(size_t)t * 512 + n] = (Ff * ef + Fr * er) / (ef + er);
      }
    }
}

// ---------------------------------------------------------------------------
// Launch. Workspace layout (bytes):
//   0: xb 4MB | 4: Qb 4MB | 8: Kb 4MB | 12: Vtb 4MB | 16: Tfb 4MB | 20: Trb 4MB
//   24: wt 3.5MB | 28: Mu8 4MB | 32: invZg 128KB
// ---------------------------------------------------------------------------
extern "C" void kernel_launch(void* const* d_in, const int* in_sizes, int n_in,
                              void* d_out, int out_size, void* d_ws, size_t ws_size,
                              hipStream_t stream) {
  const float* x   = (const float*)d_in[0];
  const float* Wq  = (const float*)d_in[1];
  const float* bq  = (const float*)d_in[2];
  const float* Wk  = (const float*)d_in[3];
  const float* bk  = (const float*)d_in[4];
  const float* Wv  = (const float*)d_in[5];
  const float* bv  = (const float*)d_in[6];
  const float* cw  = (const float*)d_in[7];
  const float* cb  = (const float*)d_in[8];
  const float* Wfh = (const float*)d_in[9];
  const float* bfh = (const float*)d_in[10];
  const float* Wfg = (const float*)d_in[11];
  const float* bfg = (const float*)d_in[12];
  const float* Wrh = (const float*)d_in[13];
  const float* brh = (const float*)d_in[14];
  const float* Wrg = (const float*)d_in[15];
  const float* brg = (const float*)d_in[16];

  char* ws = (char*)d_ws;
  const size_t MB = 1024 * 1024;
  unsigned short* xb  = (unsigned short*)(ws + 0 * MB);
  unsigned short* Qb  = (unsigned short*)(ws + 4 * MB);
  unsigned short* Kb  = (unsigned short*)(ws + 8 * MB);
  unsigned short* Vtb = (unsigned short*)(ws + 12 * MB);
  unsigned short* Tfb = (unsigned short*)(ws + 16 * MB);
  unsigned short* Trb = (unsigned short*)(ws + 20 * MB);
  unsigned short* wt  = (unsigned short*)(ws + 24 * MB);
  unsigned char*  Mu8 = (unsigned char*)(ws + 28 * MB);
  float*          invZg = (float*)(ws + 32 * MB);
  const size_t WSZ = 512 * 512;

  prep_kernel<<<512, 256, 0, stream>>>(x, Wq, Wk, Wv, Wfh, Wfg, Wrh, Wrg, xb, wt);
  qkv_kernel<<<dim3(8, 64), 256, 0, stream>>>(xb, wt + 0 * WSZ, wt + 1 * WSZ, wt + 2 * WSZ,
                                              bq, bk, bv, Qb, Kb, Vtb);
  zmask_kernel<<<dim3(8, 32), 512, 0, stream>>>(Qb, Kb, cw, cb, Mu8, invZg);
  pv_kernel<<<dim3(8, 64), 256, 0, stream>>>(Qb, Kb, Vtb, Mu8, invZg, Tfb, Trb);
  final_kernel<<<dim3(8, 64), 256, 0, stream>>>(Tfb, Trb, wt + 3 * WSZ, wt + 4 * WSZ,
                                                wt + 5 * WSZ, wt + 6 * WSZ,
                                                bfh, bfg, brh, brg, (float*)d_out);
}

// Round 5
// 239.990 us; speedup vs baseline: 1.4106x; 1.4106x over previous
//
#include <hip/hip_runtime.h>
#include <hip/hip_bf16.h>
#include <stdint.h>

typedef short bf16x8 __attribute__((ext_vector_type(8)));
typedef float f32x4 __attribute__((ext_vector_type(4)));

__device__ __forceinline__ unsigned short f2bf(float f) {
  union { float f; unsigned int u; } v;
  v.f = f;
  unsigned int u = v.u;
  u = (u + 0x7fffu + ((u >> 16) & 1u)) >> 16;  // RNE
  return (unsigned short)u;
}

__device__ __forceinline__ float asf(unsigned int u) {
  union { unsigned int u; float f; } v; v.u = u; return v.f;
}

__device__ __forceinline__ unsigned int pack_bf16(float x, float y) {
  return (unsigned int)f2bf(x) | ((unsigned int)f2bf(y) << 16);
}

typedef union { bf16x8 v; unsigned int u[4]; } frag_u;

// global->LDS async copy, 16B per lane.
__device__ __forceinline__ void gload16(const void* g, void* lds) {
  __builtin_amdgcn_global_load_lds(
      (const __attribute__((address_space(1))) unsigned int*)(unsigned long long)g,
      (__attribute__((address_space(3))) unsigned int*)(unsigned long long)(unsigned)(unsigned long long)lds,
      16, 0, 0);
}

__device__ __forceinline__ bf16x8 lds_frag(const unsigned short* t, int row, int ch4q) {
  return *(const bf16x8*)(t + row * 64 + ((ch4q ^ (row & 7)) << 3));
}

// Fragment layout index helpers (element = short):
//  Qfrag/Kfrag[b][t16][h][sub][lane]: ((b*64+t16)*8192) + h*1024 + sub*512 + lane*8
//  Vfrag[b][h][kt][dm][lane]:         (((b*8+h)*64+kt)*4+dm)*256 + lane*4
//  Mfrag (u32)[b][qt][kt][lane]:      ((b*64+qt)*64+kt)*64 + lane

// ---------------------------------------------------------------------------
// Kernel 1: prep — x -> bf16, 7 weights -> transposed bf16 (Wt[n][k] = W[k][n])
// ---------------------------------------------------------------------------
__global__ __launch_bounds__(256) void prep_kernel(
    const float* __restrict__ x,
    const float* __restrict__ Wq, const float* __restrict__ Wk, const float* __restrict__ Wv,
    const float* __restrict__ Wfh, const float* __restrict__ Wfg,
    const float* __restrict__ Wrh, const float* __restrict__ Wrg,
    unsigned short* __restrict__ xb, unsigned short* __restrict__ wt) {
  int bid = blockIdx.x;
  int tid = threadIdx.x;
  if (bid < 448) {
    __shared__ float tile[64][65];
    int mat = bid >> 6;
    int t = bid & 63;
    int tr = (t >> 3) * 64, tc = (t & 7) * 64;
    const float* W = (mat == 0) ? Wq : (mat == 1) ? Wk : (mat == 2) ? Wv
                   : (mat == 3) ? Wfh : (mat == 4) ? Wfg : (mat == 5) ? Wrh : Wrg;
    unsigned short* Wt = wt + (size_t)mat * 512 * 512;
    for (int rep = 0; rep < 16; rep++) {
      int idx = rep * 256 + tid;
      int r = idx >> 6, c = idx & 63;
      tile[r][c] = W[(tr + r) * 512 + tc + c];
    }
    __syncthreads();
    for (int rep = 0; rep < 16; rep++) {
      int idx = rep * 256 + tid;
      int r = idx >> 6, c = idx & 63;
      Wt[(tc + r) * 512 + tr + c] = f2bf(tile[c][r]);
    }
  } else {
    int blk = bid - 448;
    const float4* xi = (const float4*)x;
    for (int rep = 0; rep < 32; rep++) {
      int i = blk * 256 + tid + rep * 16384;
      float4 v = xi[i];
      unsigned int lo = (unsigned int)f2bf(v.x) | ((unsigned int)f2bf(v.y) << 16);
      unsigned int hi = (unsigned int)f2bf(v.z) | ((unsigned int)f2bf(v.w) << 16);
      uint2 u; u.x = lo; u.y = hi;
      *(uint2*)&xb[(size_t)i * 4] = u;
    }
  }
}

// ---------------------------------------------------------------------------
// Kernel 2: QKV projection, LDS-staged GEMM; epilogue emits fragment layouts
// (Qfrag/Kfrag/Vfrag) with fully coalesced lane-ordered writes.
// grid (8 nb = head, 64 mt), 256 threads.
// ---------------------------------------------------------------------------
__global__ __launch_bounds__(256, 2) void qkv_kernel(
    const unsigned short* __restrict__ xb,
    const unsigned short* __restrict__ wtq, const unsigned short* __restrict__ wtk,
    const unsigned short* __restrict__ wtv,
    const float* __restrict__ bq, const float* __restrict__ bk, const float* __restrict__ bv,
    unsigned short* __restrict__ Qfrag, unsigned short* __restrict__ Kfrag,
    unsigned short* __restrict__ Vfrag) {
  __shared__ unsigned short As[64 * 64];
  __shared__ unsigned short Bq[64 * 64];
  __shared__ unsigned short Bk[64 * 64];
  __shared__ unsigned short Bv[64 * 64];
  __shared__ __attribute__((aligned(16))) unsigned short st[3][64 * 72];
  const int m0 = blockIdx.y * 64, n0 = blockIdx.x * 64;
  const int tid = threadIdx.x, w = tid >> 6, lane = tid & 63;
  const int c = lane & 15, quad = lane >> 4;
  const int wm = w & 1, wn = w >> 1;
  const int rsel = lane >> 3, csel = lane & 7;
  const int sc = csel ^ rsel;
  const char* Ag  = (const char*)xb  + (size_t)(m0 + w * 16 + rsel) * 1024 + sc * 16;
  const char* Bgq = (const char*)wtq + (size_t)(n0 + w * 16 + rsel) * 1024 + sc * 16;
  const char* Bgk = (const char*)wtk + (size_t)(n0 + w * 16 + rsel) * 1024 + sc * 16;
  const char* Bgv = (const char*)wtv + (size_t)(n0 + w * 16 + rsel) * 1024 + sc * 16;
  unsigned short* lA = &As[w * 1024];
  unsigned short* lQ = &Bq[w * 1024];
  unsigned short* lK = &Bk[w * 1024];
  unsigned short* lV = &Bv[w * 1024];

  f32x4 acc[3][2][2];
  f32x4 z4 = {0.f, 0.f, 0.f, 0.f};
#pragma unroll
  for (int o = 0; o < 3; o++)
#pragma unroll
    for (int i = 0; i < 2; i++)
#pragma unroll
      for (int j = 0; j < 2; j++) acc[o][i][j] = z4;

  for (int ks = 0; ks < 8; ks++) {
    if (ks) __syncthreads();
    const int kb = ks * 128;
    gload16(Ag + kb, lA);        gload16(Ag + kb + 8192, lA + 512);
    gload16(Bgq + kb, lQ);       gload16(Bgq + kb + 8192, lQ + 512);
    gload16(Bgk + kb, lK);       gload16(Bgk + kb + 8192, lK + 512);
    gload16(Bgv + kb, lV);       gload16(Bgv + kb + 8192, lV + 512);
    __syncthreads();
#pragma unroll
    for (int ch = 0; ch < 2; ch++) {
      const int cq = ch * 4 + quad;
      bf16x8 a0 = lds_frag(As, wm * 32 + c, cq);
      bf16x8 a1 = lds_frag(As, wm * 32 + 16 + c, cq);
#pragma unroll
      for (int nt = 0; nt < 2; nt++) {
        const int rb = wn * 32 + nt * 16 + c;
        bf16x8 fq = lds_frag(Bq, rb, cq);
        bf16x8 fk = lds_frag(Bk, rb, cq);
        bf16x8 fv = lds_frag(Bv, rb, cq);
        acc[0][0][nt] = __builtin_amdgcn_mfma_f32_16x16x32_bf16(a0, fq, acc[0][0][nt], 0, 0, 0);
        acc[0][1][nt] = __builtin_amdgcn_mfma_f32_16x16x32_bf16(a1, fq, acc[0][1][nt], 0, 0, 0);
        acc[1][0][nt] = __builtin_amdgcn_mfma_f32_16x16x32_bf16(a0, fk, acc[1][0][nt], 0, 0, 0);
        acc[1][1][nt] = __builtin_amdgcn_mfma_f32_16x16x32_bf16(a1, fk, acc[1][1][nt], 0, 0, 0);
        acc[2][0][nt] = __builtin_amdgcn_mfma_f32_16x16x32_bf16(a0, fv, acc[2][0][nt], 0, 0, 0);
        acc[2][1][nt] = __builtin_amdgcn_mfma_f32_16x16x32_bf16(a1, fv, acc[2][1][nt], 0, 0, 0);
      }
    }
  }

  // stage: st[0]=Q[t][d], st[1]=K[t][d], st[2]=V[d][t]
#pragma unroll
  for (int ms = 0; ms < 2; ms++)
#pragma unroll
    for (int nt = 0; nt < 2; nt++) {
      int n_l = wn * 32 + nt * 16 + c;
      int n = n0 + n_l;
      float biasq = bq[n], biask = bk[n], biasv = bv[n];
#pragma unroll
      for (int r = 0; r < 4; r++) {
        int m_l = wm * 32 + ms * 16 + quad * 4 + r;
        st[0][m_l * 72 + n_l] = f2bf((acc[0][ms][nt][r] + biasq) * 0.125f);
        st[1][m_l * 72 + n_l] = f2bf(acc[1][ms][nt][r] + biask);
        st[2][n_l * 72 + m_l] = f2bf(acc[2][ms][nt][r] + biasv);
      }
    }
  __syncthreads();

  {
    const int h = n0 >> 6;
    const int bb = m0 >> 10, t0b = (m0 & 1023) >> 4;  // first 16-tile of this block
    // Q/K fragments: wave w handles tile t0b + w, subs 0/1
#pragma unroll
    for (int sub = 0; sub < 2; sub++) {
      uint4 vq = *(uint4*)&st[0][(w * 16 + c) * 72 + sub * 32 + quad * 8];
      uint4 vk = *(uint4*)&st[1][(w * 16 + c) * 72 + sub * 32 + quad * 8];
      size_t base = (size_t)((bb * 64 + t0b + w) * 8192) + h * 1024 + sub * 512 + lane * 8;
      *(uint4*)&Qfrag[base] = vq;
      *(uint4*)&Kfrag[base] = vk;
    }
    // V fragments: wave w handles kt = t0b + w, dm 0..3
#pragma unroll
    for (int dm = 0; dm < 4; dm++) {
      uint2 vv = *(uint2*)&st[2][(dm * 16 + c) * 72 + w * 16 + quad * 4];
      size_t base = (size_t)((((bb * 8 + h) * 64 + t0b + w) * 4 + dm) * 256) + lane * 4;
      *(uint2*)&Vfrag[base] = vv;
    }
  }
}

// ---------------------------------------------------------------------------
// Kernel 3: zpass1 — partial softmax denominators. grid (8 = b*2+khalf, 64 qt),
// 512 thr (8 waves x 4 kt each = 512 k per block). All loads lane-coalesced.
// ---------------------------------------------------------------------------
__global__ __launch_bounds__(512, 4) void zpass1_kernel(
    const unsigned short* __restrict__ Qfrag, const unsigned short* __restrict__ Kfrag,
    float* __restrict__ Zpart) {
  const int b = blockIdx.x >> 1, khalf = blockIdx.x & 1;
  const int qt = blockIdx.y;
  const int tid = threadIdx.x, w = tid >> 6, lane = tid & 63;
  const int c = lane & 15, quad = lane >> 4;
  __shared__ float zl[8][16];
  if (tid < 128) ((float*)zl)[tid] = 0.f;
  __syncthreads();

  f32x4 z4 = {0.f, 0.f, 0.f, 0.f};
  const size_t qbase = (size_t)((b * 64 + qt) * 8192) + lane * 8;
  bf16x8 qf[8][2];
#pragma unroll
  for (int h = 0; h < 8; h++) {
    qf[h][0] = *(const bf16x8*)&Qfrag[qbase + h * 1024];
    qf[h][1] = *(const bf16x8*)&Qfrag[qbase + h * 1024 + 512];
  }

  float zp[8] = {0, 0, 0, 0, 0, 0, 0, 0};
  for (int i = 0; i < 4; i++) {
    const int kt = khalf * 32 + w * 4 + i;
    const size_t kbase = (size_t)((b * 64 + kt) * 8192) + lane * 8;
#pragma unroll
    for (int h = 0; h < 8; h++) {
      bf16x8 kf0 = *(const bf16x8*)&Kfrag[kbase + h * 1024];
      bf16x8 kf1 = *(const bf16x8*)&Kfrag[kbase + h * 1024 + 512];
      f32x4 s = __builtin_amdgcn_mfma_f32_16x16x32_bf16(kf0, qf[h][0], z4, 0, 0, 0);
      s = __builtin_amdgcn_mfma_f32_16x16x32_bf16(kf1, qf[h][1], s, 0, 0, 0);
      zp[h] += __expf(s[0]) + __expf(s[1]) + __expf(s[2]) + __expf(s[3]);
    }
  }
#pragma unroll
  for (int h = 0; h < 8; h++) {
    float z = zp[h];
    z += __shfl_xor(z, 16); z += __shfl_xor(z, 32);
    if (quad == 0) atomicAdd(&zl[h][c], z);
  }
  __syncthreads();
  if (tid < 128) {
    int h = tid >> 4, q = tid & 15;
    Zpart[(size_t)((b * 64 + qt) * 8 + h) * 32 + khalf * 16 + q] = zl[h][q];
  }
}

// ---------------------------------------------------------------------------
// Kernel 4: zpass2 — gate + mask bytes. Same grid; ZERO LDS, ZERO barriers.
// cw[h]*invZ[h] folded into one constant per head.
// ---------------------------------------------------------------------------
__global__ __launch_bounds__(512, 4) void zpass2_kernel(
    const unsigned short* __restrict__ Qfrag, const unsigned short* __restrict__ Kfrag,
    const float* __restrict__ Zpart,
    const float* __restrict__ conv_w, const float* __restrict__ conv_b,
    unsigned int* __restrict__ Mfrag) {
  const int b = blockIdx.x >> 1, khalf = blockIdx.x & 1;
  const int qt = blockIdx.y;
  const int tid = threadIdx.x, w = tid >> 6, lane = tid & 63;
  const int c = lane & 15, quad = lane >> 4;

  f32x4 z4 = {0.f, 0.f, 0.f, 0.f};
  const float cb = conv_b[0];
  float cwz[8];
#pragma unroll
  for (int h = 0; h < 8; h++) {
    const float* zp = &Zpart[(size_t)((b * 64 + qt) * 8 + h) * 32];
    cwz[h] = conv_w[h] / (zp[c] + zp[16 + c]);
  }

  const size_t qbase = (size_t)((b * 64 + qt) * 8192) + lane * 8;
  bf16x8 qf[8][2];
#pragma unroll
  for (int h = 0; h < 8; h++) {
    qf[h][0] = *(const bf16x8*)&Qfrag[qbase + h * 1024];
    qf[h][1] = *(const bf16x8*)&Qfrag[qbase + h * 1024 + 512];
  }

  for (int i = 0; i < 4; i++) {
    const int kt = khalf * 32 + w * 4 + i;
    const size_t kbase = (size_t)((b * 64 + kt) * 8192) + lane * 8;
    f32x4 zc = {cb, cb, cb, cb};
#pragma unroll
    for (int h = 0; h < 8; h++) {
      bf16x8 kf0 = *(const bf16x8*)&Kfrag[kbase + h * 1024];
      bf16x8 kf1 = *(const bf16x8*)&Kfrag[kbase + h * 1024 + 512];
      f32x4 s = __builtin_amdgcn_mfma_f32_16x16x32_bf16(kf0, qf[h][0], z4, 0, 0, 0);
      s = __builtin_amdgcn_mfma_f32_16x16x32_bf16(kf1, qf[h][1], s, 0, 0, 0);
      zc[0] += cwz[h] * __expf(s[0]);
      zc[1] += cwz[h] * __expf(s[1]);
      zc[2] += cwz[h] * __expf(s[2]);
      zc[3] += cwz[h] * __expf(s[3]);
    }
    unsigned int packed = 0;
#pragma unroll
    for (int r = 0; r < 4; r++) {
      unsigned int m = (zc[r] <= 0.f ? 1u : 0u) | (zc[r] >= 0.f ? 2u : 0u);
      packed |= m << (8 * r);
    }
    Mfrag[(size_t)((b * 64 + qt) * 64 + kt) * 64 + lane] = packed;
  }
}

// ---------------------------------------------------------------------------
// Kernel 5: pv — grid (8 h, 64 = b*16 + q64blk), 256 thr. Barrier-free main
// loop, every load lane-coalesced (Kfrag 16B, Mfrag 4B, Vfrag 8B).
// ---------------------------------------------------------------------------
__global__ __launch_bounds__(256, 2) void pv_kernel(
    const unsigned short* __restrict__ Qfrag, const unsigned short* __restrict__ Kfrag,
    const unsigned short* __restrict__ Vfrag,
    const unsigned int* __restrict__ Mfrag, const float* __restrict__ Zpart,
    unsigned short* __restrict__ Tfb, unsigned short* __restrict__ Trb) {
  const int h = blockIdx.x;
  const int b = blockIdx.y >> 4, q64 = blockIdx.y & 15;
  const int tid = threadIdx.x, w = tid >> 6, lane = tid & 63;
  const int c = lane & 15, quad = lane >> 4;
  const int qt = q64 * 4 + w;

  __shared__ __attribute__((aligned(16))) unsigned short tsf[64 * 72];
  __shared__ __attribute__((aligned(16))) unsigned short tsr[64 * 72];

  f32x4 z4 = {0.f, 0.f, 0.f, 0.f};
  const size_t qbase = (size_t)((b * 64 + qt) * 8192) + h * 1024 + lane * 8;
  bf16x8 qf0 = *(const bf16x8*)&Qfrag[qbase];
  bf16x8 qf1 = *(const bf16x8*)&Qfrag[qbase + 512];
  const float* zpp = &Zpart[(size_t)((b * 64 + qt) * 8 + h) * 32];
  const float invZ = 1.0f / (zpp[c] + zpp[16 + c]);
  const unsigned int* mrow = &Mfrag[(size_t)((b * 64 + qt) * 64) * 64 + lane];
  const size_t vbase = (size_t)((b * 8 + h) * 64) * 1024 + lane * 4;

  f32x4 accf[4], accr[4];
#pragma unroll
  for (int i = 0; i < 4; i++) { accf[i] = z4; accr[i] = z4; }
  float zf = 0.f, zr = 0.f;

  for (int kt = 0; kt < 64; kt++) {
    const size_t kbase = (size_t)((b * 64 + kt) * 8192) + h * 1024 + lane * 8;
    bf16x8 kf0 = *(const bf16x8*)&Kfrag[kbase];
    bf16x8 kf1 = *(const bf16x8*)&Kfrag[kbase + 512];
    f32x4 s = __builtin_amdgcn_mfma_f32_16x16x32_bf16(kf0, qf0, z4, 0, 0, 0);
    s = __builtin_amdgcn_mfma_f32_16x16x32_bf16(kf1, qf1, s, 0, 0, 0);
    const unsigned int mb = mrow[kt * 64];
    float ea[4];
#pragma unroll
    for (int r = 0; r < 4; r++) ea[r] = __expf(__expf(s[r]) * invZ);
    frag_u pF, pR;
    pF.u[0] = pack_bf16((mb & 0x1u) ? ea[0] : 1.f, (mb & 0x100u) ? ea[1] : 1.f);
    pF.u[1] = pack_bf16((mb & 0x10000u) ? ea[2] : 1.f, (mb & 0x1000000u) ? ea[3] : 1.f);
    pF.u[2] = 0; pF.u[3] = 0;
    pR.u[0] = pack_bf16((mb & 0x2u) ? ea[0] : 1.f, (mb & 0x200u) ? ea[1] : 1.f);
    pR.u[1] = pack_bf16((mb & 0x20000u) ? ea[2] : 1.f, (mb & 0x2000000u) ? ea[3] : 1.f);
    pR.u[2] = 0; pR.u[3] = 0;
    zf += asf(pF.u[0] << 16) + asf(pF.u[0] & 0xffff0000u)
        + asf(pF.u[1] << 16) + asf(pF.u[1] & 0xffff0000u);
    zr += asf(pR.u[0] << 16) + asf(pR.u[0] & 0xffff0000u)
        + asf(pR.u[1] << 16) + asf(pR.u[1] & 0xffff0000u);
#pragma unroll
    for (int dm = 0; dm < 4; dm++) {
      frag_u vf;
      uint2 vv = *(const uint2*)&Vfrag[vbase + (size_t)(kt * 4 + dm) * 256];
      vf.u[0] = vv.x; vf.u[1] = vv.y; vf.u[2] = 0; vf.u[3] = 0;
      accf[dm] = __builtin_amdgcn_mfma_f32_16x16x32_bf16(vf.v, pF.v, accf[dm], 0, 0, 0);
      accr[dm] = __builtin_amdgcn_mfma_f32_16x16x32_bf16(vf.v, pR.v, accr[dm], 0, 0, 0);
    }
  }

  zf += __shfl_xor(zf, 16); zf += __shfl_xor(zf, 32);
  zr += __shfl_xor(zr, 16); zr += __shfl_xor(zr, 32);
  const float izf = 1.0f / zf, izr = 1.0f / zr;
  const int qrow_l = w * 16 + c;
#pragma unroll
  for (int dm = 0; dm < 4; dm++) {
    uint2 u;
    u.x = pack_bf16(accf[dm][0] * izf, accf[dm][1] * izf);
    u.y = pack_bf16(accf[dm][2] * izf, accf[dm][3] * izf);
    *(uint2*)&tsf[qrow_l * 72 + dm * 16 + quad * 4] = u;
    u.x = pack_bf16(accr[dm][0] * izr, accr[dm][1] * izr);
    u.y = pack_bf16(accr[dm][2] * izr, accr[dm][3] * izr);
    *(uint2*)&tsr[qrow_l * 72 + dm * 16 + quad * 4] = u;
  }
  __syncthreads();
  {
    const int row = tid >> 2, seg = tid & 3;
    const size_t g = (size_t)(b * 1024 + q64 * 64 + row) * 512 + h * 64 + seg * 16;
    uint4 a0 = *(uint4*)&tsf[row * 72 + seg * 16];
    uint4 a1 = *(uint4*)&tsf[row * 72 + seg * 16 + 8];
    *(uint4*)&Tfb[g] = a0; *(uint4*)&Tfb[g + 8] = a1;
    a0 = *(uint4*)&tsr[row * 72 + seg * 16];
    a1 = *(uint4*)&tsr[row * 72 + seg * 16 + 8];
    *(uint4*)&Trb[g] = a0; *(uint4*)&Trb[g + 8] = a1;
  }
}

// ---------------------------------------------------------------------------
// Kernel 6: final — LDS-staged fused 4-GEMM + gate combine. grid (8 nb, 64 mt).
// ---------------------------------------------------------------------------
__global__ __launch_bounds__(256, 2) void final_kernel(
    const unsigned short* __restrict__ Tfb, const unsigned short* __restrict__ Trb,
    const unsigned short* __restrict__ wfh, const unsigned short* __restrict__ wfg,
    const unsigned short* __restrict__ wrh, const unsigned short* __restrict__ wrg,
    const float* __restrict__ bfh, const float* __restrict__ bfg,
    const float* __restrict__ brh, const float* __restrict__ brg,
    float* __restrict__ out) {
  __shared__ unsigned short Atf[64 * 64];
  __shared__ unsigned short Atr[64 * 64];
  __shared__ unsigned short Bfh[64 * 64];
  __shared__ unsigned short Bfg[64 * 64];
  __shared__ unsigned short Brh[64 * 64];
  __shared__ unsigned short Brg[64 * 64];
  const int m0 = blockIdx.y * 64, n0 = blockIdx.x * 64;
  const int tid = threadIdx.x, w = tid >> 6, lane = tid & 63;
  const int c = lane & 15, quad = lane >> 4;
  const int wm = w & 1, wn = w >> 1;
  const int rsel = lane >> 3, csel = lane & 7;
  const int sc = csel ^ rsel;
  const char* Agf = (const char*)Tfb + (size_t)(m0 + w * 16 + rsel) * 1024 + sc * 16;
  const char* Agr = (const char*)Trb + (size_t)(m0 + w * 16 + rsel) * 1024 + sc * 16;
  const char* Bg0 = (const char*)wfh + (size_t)(n0 + w * 16 + rsel) * 1024 + sc * 16;
  const char* Bg1 = (const char*)wfg + (size_t)(n0 + w * 16 + rsel) * 1024 + sc * 16;
  const char* Bg2 = (const char*)wrh + (size_t)(n0 + w * 16 + rsel) * 1024 + sc * 16;
  const char* Bg3 = (const char*)wrg + (size_t)(n0 + w * 16 + rsel) * 1024 + sc * 16;
  unsigned short* lAf = &Atf[w * 1024];
  unsigned short* lAr = &Atr[w * 1024];
  unsigned short* l0 = &Bfh[w * 1024];
  unsigned short* l1 = &Bfg[w * 1024];
  unsigned short* l2 = &Brh[w * 1024];
  unsigned short* l3 = &Brg[w * 1024];

  f32x4 acc[4][2][2];
  f32x4 z4 = {0.f, 0.f, 0.f, 0.f};
#pragma unroll
  for (int o = 0; o < 4; o++)
#pragma unroll
    for (int i = 0; i < 2; i++)
#pragma unroll
      for (int j = 0; j < 2; j++) acc[o][i][j] = z4;

  for (int ks = 0; ks < 8; ks++) {
    if (ks) __syncthreads();
    const int kb = ks * 128;
    gload16(Agf + kb, lAf);  gload16(Agf + kb + 8192, lAf + 512);
    gload16(Agr + kb, lAr);  gload16(Agr + kb + 8192, lAr + 512);
    gload16(Bg0 + kb, l0);   gload16(Bg0 + kb + 8192, l0 + 512);
    gload16(Bg1 + kb, l1);   gload16(Bg1 + kb + 8192, l1 + 512);
    gload16(Bg2 + kb, l2);   gload16(Bg2 + kb + 8192, l2 + 512);
    gload16(Bg3 + kb, l3);   gload16(Bg3 + kb + 8192, l3 + 512);
    __syncthreads();
#pragma unroll
    for (int ch = 0; ch < 2; ch++) {
      const int cq = ch * 4 + quad;
      bf16x8 af0 = lds_frag(Atf, wm * 32 + c, cq);
      bf16x8 af1 = lds_frag(Atf, wm * 32 + 16 + c, cq);
      bf16x8 ar0 = lds_frag(Atr, wm * 32 + c, cq);
      bf16x8 ar1 = lds_frag(Atr, wm * 32 + 16 + c, cq);
#pragma unroll
      for (int nt = 0; nt < 2; nt++) {
        const int rb = wn * 32 + nt * 16 + c;
        bf16x8 f0 = lds_frag(Bfh, rb, cq);
        bf16x8 f1 = lds_frag(Bfg, rb, cq);
        bf16x8 f2 = lds_frag(Brh, rb, cq);
        bf16x8 f3 = lds_frag(Brg, rb, cq);
        acc[0][0][nt] = __builtin_amdgcn_mfma_f32_16x16x32_bf16(af0, f0, acc[0][0][nt], 0, 0, 0);
        acc[0][1][nt] = __builtin_amdgcn_mfma_f32_16x16x32_bf16(af1, f0, acc[0][1][nt], 0, 0, 0);
        acc[1][0][nt] = __builtin_amdgcn_mfma_f32_16x16x32_bf16(af0, f1, acc[1][0][nt], 0, 0, 0);
        acc[1][1][nt] = __builtin_amdgcn_mfma_f32_16x16x32_bf16(af1, f1, acc[1][1][nt], 0, 0, 0);
        acc[2][0][nt] = __builtin_amdgcn_mfma_f32_16x16x32_bf16(ar0, f2, acc[2][0][nt], 0, 0, 0);
        acc[2][1][nt] = __builtin_amdgcn_mfma_f32_16x16x32_bf16(ar1, f2, acc[2][1][nt], 0, 0, 0);
        acc[3][0][nt] = __builtin_amdgcn_mfma_f32_16x16x32_bf16(ar0, f3, acc[3][0][nt], 0, 0, 0);
        acc[3][1][nt] = __builtin_amdgcn_mfma_f32_16x16x32_bf16(ar1, f3, acc[3][1][nt], 0, 0, 0);
      }
    }
  }

#pragma unroll
  for (int ms = 0; ms < 2; ms++)
#pragma unroll
    for (int nt = 0; nt < 2; nt++) {
      int n = n0 + wn * 32 + nt * 16 + c;
      float b0 = bfh[n], b1 = bfg[n], b2 = brh[n], b3 = brg[n];
      int t0 = m0 + wm * 32 + ms * 16 + quad * 4;
#pragma unroll
      for (int r = 0; r < 4; r++) {
        int t = t0 + r;
        float Ff = acc[0][ms][nt][r] + b0;
        float Gf = 1.0f / (1.0f + __expf(-(acc[1][ms][nt][r] + b1)));
        float Fr = acc[2][ms][nt][r] + b2;
        float Gr = 1.0f / (1.0f + __expf(-(acc[3][ms][nt][r] + b3)));
        float ef = __expf(Gf), er = __expf(Gr);
        out[(size_t)t * 512 + n] = (Ff * ef + Fr * er) / (ef + er);
      }
    }
}

// ---------------------------------------------------------------------------
// Launch. Workspace (bytes):
//   0: xb 4MB | 4: Qfrag 4MB | 8: Kfrag 4MB | 12: Vfrag 4MB
//   16: Tfb 4MB | 20: Trb 4MB | 24: wt 3.5MB | 28: Mfrag 4MB | 32: Zpart 256KB
// ---------------------------------------------------------------------------
extern "C" void kernel_launch(void* const* d_in, const int* in_sizes, int n_in,
                              void* d_out, int out_size, void* d_ws, size_t ws_size,
                              hipStream_t stream) {
  const float* x   = (const float*)d_in[0];
  const float* Wq  = (const float*)d_in[1];
  const float* bq  = (const float*)d_in[2];
  const float* Wk  = (const float*)d_in[3];
  const float* bk  = (const float*)d_in[4];
  const float* Wv  = (const float*)d_in[5];
  const float* bv  = (const float*)d_in[6];
  const float* cw  = (const float*)d_in[7];
  const float* cb  = (const float*)d_in[8];
  const float* Wfh = (const float*)d_in[9];
  const float* bfh = (const float*)d_in[10];
  const float* Wfg = (const float*)d_in[11];
  const float* bfg = (const float*)d_in[12];
  const float* Wrh = (const float*)d_in[13];
  const float* brh = (const float*)d_in[14];
  const float* Wrg = (const float*)d_in[15];
  const float* brg = (const float*)d_in[16];

  char* ws = (char*)d_ws;
  const size_t MB = 1024 * 1024;
  unsigned short* xb    = (unsigned short*)(ws + 0 * MB);
  unsigned short* Qfrag = (unsigned short*)(ws + 4 * MB);
  unsigned short* Kfrag = (unsigned short*)(ws + 8 * MB);
  unsigned short* Vfrag = (unsigned short*)(ws + 12 * MB);
  unsigned short* Tfb   = (unsigned short*)(ws + 16 * MB);
  unsigned short* Trb   = (unsigned short*)(ws + 20 * MB);
  unsigned short* wt    = (unsigned short*)(ws + 24 * MB);
  unsigned int*   Mfrag = (unsigned int*)(ws + 28 * MB);
  float*          Zpart = (float*)(ws + 32 * MB);
  const size_t WSZ = 512 * 512;

  prep_kernel<<<512, 256, 0, stream>>>(x, Wq, Wk, Wv, Wfh, Wfg, Wrh, Wrg, xb, wt);
  qkv_kernel<<<dim3(8, 64), 256, 0, stream>>>(xb, wt + 0 * WSZ, wt + 1 * WSZ, wt + 2 * WSZ,
                                              bq, bk, bv, Qfrag, Kfrag, Vfrag);
  zpass1_kernel<<<dim3(8, 64), 512, 0, stream>>>(Qfrag, Kfrag, Zpart);
  zpass2_kernel<<<dim3(8, 64), 512, 0, stream>>>(Qfrag, Kfrag, Zpart, cw, cb, Mfrag);
  pv_kernel<<<dim3(8, 64), 256, 0, stream>>>(Qfrag, Kfrag, Vfrag, Mfrag, Zpart, Tfb, Trb);
  final_kernel<<<dim3(8, 64), 256, 0, stream>>>(Tfb, Trb, wt + 3 * WSZ, wt + 4 * WSZ,
                                                wt + 5 * WSZ, wt + 6 * WSZ,
                                                bfh, bfg, brh, brg, (float*)d_out);
}

// Round 6
// 215.859 us; speedup vs baseline: 1.5683x; 1.1118x over previous
//
#include <hip/hip_runtime.h>
#include <hip/hip_bf16.h>
#include <stdint.h>

typedef short bf16x8 __attribute__((ext_vector_type(8)));
typedef float f32x4 __attribute__((ext_vector_type(4)));

__device__ __forceinline__ unsigned short f2bf(float f) {
  union { float f; unsigned int u; } v;
  v.f = f;
  unsigned int u = v.u;
  u = (u + 0x7fffu + ((u >> 16) & 1u)) >> 16;  // RNE
  return (unsigned short)u;
}

__device__ __forceinline__ unsigned int pack_bf16(float x, float y) {
  return (unsigned int)f2bf(x) | ((unsigned int)f2bf(y) << 16);
}

typedef union { bf16x8 v; unsigned int u[4]; } frag_u;

// global->LDS async copy, 16B per lane.
__device__ __forceinline__ void gload16(const void* g, void* lds) {
  __builtin_amdgcn_global_load_lds(
      (const __attribute__((address_space(1))) unsigned int*)(unsigned long long)g,
      (__attribute__((address_space(3))) unsigned int*)(unsigned long long)(unsigned)(unsigned long long)lds,
      16, 0, 0);
}

__device__ __forceinline__ bf16x8 lds_frag(const unsigned short* t, int row, int ch4q) {
  return *(const bf16x8*)(t + row * 64 + ((ch4q ^ (row & 7)) << 3));
}

// Fragment layout index helpers (element = short):
//  Qfrag/Kfrag[b][t16][h][sub][lane]: ((b*64+t16)*8192) + h*1024 + sub*512 + lane*8
//  Vfrag[b][h][kt][dm][lane]:         (((b*8+h)*64+kt)*4+dm)*256 + lane*4
//  Mfrag (u32)[b][qt][kt][lane]:      ((b*64+qt)*64+kt)*64 + lane

// ---------------------------------------------------------------------------
// Kernel 1: prep — x -> bf16, 7 weights -> transposed bf16 (Wt[n][k] = W[k][n])
// ---------------------------------------------------------------------------
__global__ __launch_bounds__(256) void prep_kernel(
    const float* __restrict__ x,
    const float* __restrict__ Wq, const float* __restrict__ Wk, const float* __restrict__ Wv,
    const float* __restrict__ Wfh, const float* __restrict__ Wfg,
    const float* __restrict__ Wrh, const float* __restrict__ Wrg,
    unsigned short* __restrict__ xb, unsigned short* __restrict__ wt) {
  int bid = blockIdx.x;
  int tid = threadIdx.x;
  if (bid < 448) {
    __shared__ float tile[64][65];
    int mat = bid >> 6;
    int t = bid & 63;
    int tr = (t >> 3) * 64, tc = (t & 7) * 64;
    const float* W = (mat == 0) ? Wq : (mat == 1) ? Wk : (mat == 2) ? Wv
                   : (mat == 3) ? Wfh : (mat == 4) ? Wfg : (mat == 5) ? Wrh : Wrg;
    unsigned short* Wt = wt + (size_t)mat * 512 * 512;
    for (int rep = 0; rep < 16; rep++) {
      int idx = rep * 256 + tid;
      int r = idx >> 6, c = idx & 63;
      tile[r][c] = W[(tr + r) * 512 + tc + c];
    }
    __syncthreads();
    for (int rep = 0; rep < 16; rep++) {
      int idx = rep * 256 + tid;
      int r = idx >> 6, c = idx & 63;
      Wt[(tc + r) * 512 + tr + c] = f2bf(tile[c][r]);
    }
  } else {
    int blk = bid - 448;
    const float4* xi = (const float4*)x;
    for (int rep = 0; rep < 32; rep++) {
      int i = blk * 256 + tid + rep * 16384;
      float4 v = xi[i];
      unsigned int lo = (unsigned int)f2bf(v.x) | ((unsigned int)f2bf(v.y) << 16);
      unsigned int hi = (unsigned int)f2bf(v.z) | ((unsigned int)f2bf(v.w) << 16);
      uint2 u; u.x = lo; u.y = hi;
      *(uint2*)&xb[(size_t)i * 4] = u;
    }
  }
}

// ---------------------------------------------------------------------------
// Kernel 2: QKV projection, LDS-staged GEMM; epilogue emits fragment layouts
// (Qfrag/Kfrag/Vfrag) with fully coalesced lane-ordered writes.
// grid (8 nb = head, 64 mt), 256 threads.
// ---------------------------------------------------------------------------
__global__ __launch_bounds__(256, 2) void qkv_kernel(
    const unsigned short* __restrict__ xb,
    const unsigned short* __restrict__ wtq, const unsigned short* __restrict__ wtk,
    const unsigned short* __restrict__ wtv,
    const float* __restrict__ bq, const float* __restrict__ bk, const float* __restrict__ bv,
    unsigned short* __restrict__ Qfrag, unsigned short* __restrict__ Kfrag,
    unsigned short* __restrict__ Vfrag) {
  __shared__ unsigned short As[64 * 64];
  __shared__ unsigned short Bq[64 * 64];
  __shared__ unsigned short Bk[64 * 64];
  __shared__ unsigned short Bv[64 * 64];
  __shared__ __attribute__((aligned(16))) unsigned short st[3][64 * 72];
  const int m0 = blockIdx.y * 64, n0 = blockIdx.x * 64;
  const int tid = threadIdx.x, w = tid >> 6, lane = tid & 63;
  const int c = lane & 15, quad = lane >> 4;
  const int wm = w & 1, wn = w >> 1;
  const int rsel = lane >> 3, csel = lane & 7;
  const int sc = csel ^ rsel;
  const char* Ag  = (const char*)xb  + (size_t)(m0 + w * 16 + rsel) * 1024 + sc * 16;
  const char* Bgq = (const char*)wtq + (size_t)(n0 + w * 16 + rsel) * 1024 + sc * 16;
  const char* Bgk = (const char*)wtk + (size_t)(n0 + w * 16 + rsel) * 1024 + sc * 16;
  const char* Bgv = (const char*)wtv + (size_t)(n0 + w * 16 + rsel) * 1024 + sc * 16;
  unsigned short* lA = &As[w * 1024];
  unsigned short* lQ = &Bq[w * 1024];
  unsigned short* lK = &Bk[w * 1024];
  unsigned short* lV = &Bv[w * 1024];

  f32x4 acc[3][2][2];
  f32x4 z4 = {0.f, 0.f, 0.f, 0.f};
#pragma unroll
  for (int o = 0; o < 3; o++)
#pragma unroll
    for (int i = 0; i < 2; i++)
#pragma unroll
      for (int j = 0; j < 2; j++) acc[o][i][j] = z4;

  for (int ks = 0; ks < 8; ks++) {
    if (ks) __syncthreads();
    const int kb = ks * 128;
    gload16(Ag + kb, lA);        gload16(Ag + kb + 8192, lA + 512);
    gload16(Bgq + kb, lQ);       gload16(Bgq + kb + 8192, lQ + 512);
    gload16(Bgk + kb, lK);       gload16(Bgk + kb + 8192, lK + 512);
    gload16(Bgv + kb, lV);       gload16(Bgv + kb + 8192, lV + 512);
    __syncthreads();
#pragma unroll
    for (int ch = 0; ch < 2; ch++) {
      const int cq = ch * 4 + quad;
      bf16x8 a0 = lds_frag(As, wm * 32 + c, cq);
      bf16x8 a1 = lds_frag(As, wm * 32 + 16 + c, cq);
#pragma unroll
      for (int nt = 0; nt < 2; nt++) {
        const int rb = wn * 32 + nt * 16 + c;
        bf16x8 fq = lds_frag(Bq, rb, cq);
        bf16x8 fk = lds_frag(Bk, rb, cq);
        bf16x8 fv = lds_frag(Bv, rb, cq);
        acc[0][0][nt] = __builtin_amdgcn_mfma_f32_16x16x32_bf16(a0, fq, acc[0][0][nt], 0, 0, 0);
        acc[0][1][nt] = __builtin_amdgcn_mfma_f32_16x16x32_bf16(a1, fq, acc[0][1][nt], 0, 0, 0);
        acc[1][0][nt] = __builtin_amdgcn_mfma_f32_16x16x32_bf16(a0, fk, acc[1][0][nt], 0, 0, 0);
        acc[1][1][nt] = __builtin_amdgcn_mfma_f32_16x16x32_bf16(a1, fk, acc[1][1][nt], 0, 0, 0);
        acc[2][0][nt] = __builtin_amdgcn_mfma_f32_16x16x32_bf16(a0, fv, acc[2][0][nt], 0, 0, 0);
        acc[2][1][nt] = __builtin_amdgcn_mfma_f32_16x16x32_bf16(a1, fv, acc[2][1][nt], 0, 0, 0);
      }
    }
  }

  // stage: st[0]=Q[t][d], st[1]=K[t][d], st[2]=V[d][t]
#pragma unroll
  for (int ms = 0; ms < 2; ms++)
#pragma unroll
    for (int nt = 0; nt < 2; nt++) {
      int n_l = wn * 32 + nt * 16 + c;
      int n = n0 + n_l;
      float biasq = bq[n], biask = bk[n], biasv = bv[n];
#pragma unroll
      for (int r = 0; r < 4; r++) {
        int m_l = wm * 32 + ms * 16 + quad * 4 + r;
        st[0][m_l * 72 + n_l] = f2bf((acc[0][ms][nt][r] + biasq) * 0.125f);
        st[1][m_l * 72 + n_l] = f2bf(acc[1][ms][nt][r] + biask);
        st[2][n_l * 72 + m_l] = f2bf(acc[2][ms][nt][r] + biasv);
      }
    }
  __syncthreads();

  {
    const int h = n0 >> 6;
    const int bb = m0 >> 10, t0b = (m0 & 1023) >> 4;
#pragma unroll
    for (int sub = 0; sub < 2; sub++) {
      uint4 vq = *(uint4*)&st[0][(w * 16 + c) * 72 + sub * 32 + quad * 8];
      uint4 vk = *(uint4*)&st[1][(w * 16 + c) * 72 + sub * 32 + quad * 8];
      size_t base = (size_t)((bb * 64 + t0b + w) * 8192) + h * 1024 + sub * 512 + lane * 8;
      *(uint4*)&Qfrag[base] = vq;
      *(uint4*)&Kfrag[base] = vk;
    }
#pragma unroll
    for (int dm = 0; dm < 4; dm++) {
      uint2 vv = *(uint2*)&st[2][(dm * 16 + c) * 72 + w * 16 + quad * 4];
      size_t base = (size_t)((((bb * 8 + h) * 64 + t0b + w) * 4 + dm) * 256) + lane * 4;
      *(uint2*)&Vfrag[base] = vv;
    }
  }
}

// ---------------------------------------------------------------------------
// Kernel 3: zpass1 — partial softmax denominators. grid (8 = b*2+khalf, 64 qt),
// 512 thr (8 waves x 4 kt each = 512 k per block). All loads lane-coalesced.
// ---------------------------------------------------------------------------
__global__ __launch_bounds__(512, 4) void zpass1_kernel(
    const unsigned short* __restrict__ Qfrag, const unsigned short* __restrict__ Kfrag,
    float* __restrict__ Zpart) {
  const int b = blockIdx.x >> 1, khalf = blockIdx.x & 1;
  const int qt = blockIdx.y;
  const int tid = threadIdx.x, w = tid >> 6, lane = tid & 63;
  const int c = lane & 15, quad = lane >> 4;
  __shared__ float zl[8][16];
  if (tid < 128) ((float*)zl)[tid] = 0.f;
  __syncthreads();

  f32x4 z4 = {0.f, 0.f, 0.f, 0.f};
  const size_t qbase = (size_t)((b * 64 + qt) * 8192) + lane * 8;
  bf16x8 qf[8][2];
#pragma unroll
  for (int h = 0; h < 8; h++) {
    qf[h][0] = *(const bf16x8*)&Qfrag[qbase + h * 1024];
    qf[h][1] = *(const bf16x8*)&Qfrag[qbase + h * 1024 + 512];
  }

  float zp[8] = {0, 0, 0, 0, 0, 0, 0, 0};
  for (int i = 0; i < 4; i++) {
    const int kt = khalf * 32 + w * 4 + i;
    const size_t kbase = (size_t)((b * 64 + kt) * 8192) + lane * 8;
#pragma unroll
    for (int h = 0; h < 8; h++) {
      bf16x8 kf0 = *(const bf16x8*)&Kfrag[kbase + h * 1024];
      bf16x8 kf1 = *(const bf16x8*)&Kfrag[kbase + h * 1024 + 512];
      f32x4 s = __builtin_amdgcn_mfma_f32_16x16x32_bf16(kf0, qf[h][0], z4, 0, 0, 0);
      s = __builtin_amdgcn_mfma_f32_16x16x32_bf16(kf1, qf[h][1], s, 0, 0, 0);
      zp[h] += __expf(s[0]) + __expf(s[1]) + __expf(s[2]) + __expf(s[3]);
    }
  }
#pragma unroll
  for (int h = 0; h < 8; h++) {
    float z = zp[h];
    z += __shfl_xor(z, 16); z += __shfl_xor(z, 32);
    if (quad == 0) atomicAdd(&zl[h][c], z);
  }
  __syncthreads();
  if (tid < 128) {
    int h = tid >> 4, q = tid & 15;
    Zpart[(size_t)((b * 64 + qt) * 8 + h) * 32 + khalf * 16 + q] = zl[h][q];
  }
}

// ---------------------------------------------------------------------------
// Kernel 4: zpass2 — gate + mask bytes. Same grid; ZERO LDS, ZERO barriers.
// cw[h]*invZ[h] folded into one constant per head.
// ---------------------------------------------------------------------------
__global__ __launch_bounds__(512, 4) void zpass2_kernel(
    const unsigned short* __restrict__ Qfrag, const unsigned short* __restrict__ Kfrag,
    const float* __restrict__ Zpart,
    const float* __restrict__ conv_w, const float* __restrict__ conv_b,
    unsigned int* __restrict__ Mfrag) {
  const int b = blockIdx.x >> 1, khalf = blockIdx.x & 1;
  const int qt = blockIdx.y;
  const int tid = threadIdx.x, w = tid >> 6, lane = tid & 63;
  const int c = lane & 15;

  f32x4 z4 = {0.f, 0.f, 0.f, 0.f};
  const float cb = conv_b[0];
  float cwz[8];
#pragma unroll
  for (int h = 0; h < 8; h++) {
    const float* zp = &Zpart[(size_t)((b * 64 + qt) * 8 + h) * 32];
    cwz[h] = conv_w[h] / (zp[c] + zp[16 + c]);
  }

  const size_t qbase = (size_t)((b * 64 + qt) * 8192) + lane * 8;
  bf16x8 qf[8][2];
#pragma unroll
  for (int h = 0; h < 8; h++) {
    qf[h][0] = *(const bf16x8*)&Qfrag[qbase + h * 1024];
    qf[h][1] = *(const bf16x8*)&Qfrag[qbase + h * 1024 + 512];
  }

  for (int i = 0; i < 4; i++) {
    const int kt = khalf * 32 + w * 4 + i;
    const size_t kbase = (size_t)((b * 64 + kt) * 8192) + lane * 8;
    f32x4 zc = {cb, cb, cb, cb};
#pragma unroll
    for (int h = 0; h < 8; h++) {
      bf16x8 kf0 = *(const bf16x8*)&Kfrag[kbase + h * 1024];
      bf16x8 kf1 = *(const bf16x8*)&Kfrag[kbase + h * 1024 + 512];
      f32x4 s = __builtin_amdgcn_mfma_f32_16x16x32_bf16(kf0, qf[h][0], z4, 0, 0, 0);
      s = __builtin_amdgcn_mfma_f32_16x16x32_bf16(kf1, qf[h][1], s, 0, 0, 0);
      zc[0] += cwz[h] * __expf(s[0]);
      zc[1] += cwz[h] * __expf(s[1]);
      zc[2] += cwz[h] * __expf(s[2]);
      zc[3] += cwz[h] * __expf(s[3]);
    }
    unsigned int packed = 0;
#pragma unroll
    for (int r = 0; r < 4; r++) {
      unsigned int m = (zc[r] <= 0.f ? 1u : 0u) | (zc[r] >= 0.f ? 2u : 0u);
      packed |= m << (8 * r);
    }
    Mfrag[(size_t)((b * 64 + qt) * 64 + kt) * 64 + lane] = packed;
  }
}

// ---------------------------------------------------------------------------
// Kernel 5: pv — grid (8 h, 128 = b*32+qb), 256 thr = 4 waves =
// (2 q-tiles x 2 k-halves). 4 blocks/CU -> 16 waves/CU. Barrier-free main
// loop; denominators via ones-row MFMA; phased LDS combine in the epilogue.
// ---------------------------------------------------------------------------
__global__ __launch_bounds__(256, 4) void pv_kernel(
    const unsigned short* __restrict__ Qfrag, const unsigned short* __restrict__ Kfrag,
    const unsigned short* __restrict__ Vfrag,
    const unsigned int* __restrict__ Mfrag, const float* __restrict__ Zpart,
    unsigned short* __restrict__ Tfb, unsigned short* __restrict__ Trb) {
  const int h = blockIdx.x;
  const int b = blockIdx.y >> 5, qb = blockIdx.y & 31;
  const int tid = threadIdx.x, w = tid >> 6, lane = tid & 63;
  const int c = lane & 15, quad = lane >> 4;
  const int qloc = w & 1, kh = w >> 1;
  const int qt = qb * 2 + qloc;

  __shared__ __attribute__((aligned(16))) float red[2][4][256][4];  // 32 KB, reused
  __shared__ float zb[2][2][16];

  f32x4 z4 = {0.f, 0.f, 0.f, 0.f};
  const size_t qbase = (size_t)((b * 64 + qt) * 8192) + h * 1024 + lane * 8;
  bf16x8 qf0 = *(const bf16x8*)&Qfrag[qbase];
  bf16x8 qf1 = *(const bf16x8*)&Qfrag[qbase + 512];
  const float* zpp = &Zpart[(size_t)((b * 64 + qt) * 8 + h) * 32];
  const float invZ = 1.0f / (zpp[c] + zpp[16 + c]);
  const unsigned int* mrow = &Mfrag[(size_t)((b * 64 + qt) * 64) * 64 + lane];
  const size_t vbase = (size_t)((b * 8 + h) * 64) * 1024 + lane * 4;

  frag_u ones;
  ones.u[0] = 0x3F803F80u; ones.u[1] = 0x3F803F80u;
  ones.u[2] = 0x3F803F80u; ones.u[3] = 0x3F803F80u;

  f32x4 accf[4], accr[4];
#pragma unroll
  for (int i = 0; i < 4; i++) { accf[i] = z4; accr[i] = z4; }
  f32x4 acc_zf = z4, acc_zr = z4;

#pragma unroll 2
  for (int kt = kh * 32; kt < kh * 32 + 32; kt++) {
    const size_t kbase = (size_t)((b * 64 + kt) * 8192) + h * 1024 + lane * 8;
    bf16x8 kf0 = *(const bf16x8*)&Kfrag[kbase];
    bf16x8 kf1 = *(const bf16x8*)&Kfrag[kbase + 512];
    f32x4 s = __builtin_amdgcn_mfma_f32_16x16x32_bf16(kf0, qf0, z4, 0, 0, 0);
    s = __builtin_amdgcn_mfma_f32_16x16x32_bf16(kf1, qf1, s, 0, 0, 0);
    const unsigned int mb = mrow[kt * 64];
    float ea[4];
#pragma unroll
    for (int r = 0; r < 4; r++) ea[r] = __expf(__expf(s[r]) * invZ);
    frag_u pF, pR;
    pF.u[0] = pack_bf16((mb & 0x1u) ? ea[0] : 1.f, (mb & 0x100u) ? ea[1] : 1.f);
    pF.u[1] = pack_bf16((mb & 0x10000u) ? ea[2] : 1.f, (mb & 0x1000000u) ? ea[3] : 1.f);
    pF.u[2] = 0; pF.u[3] = 0;
    pR.u[0] = pack_bf16((mb & 0x2u) ? ea[0] : 1.f, (mb & 0x200u) ? ea[1] : 1.f);
    pR.u[1] = pack_bf16((mb & 0x20000u) ? ea[2] : 1.f, (mb & 0x2000000u) ? ea[3] : 1.f);
    pR.u[2] = 0; pR.u[3] = 0;
    acc_zf = __builtin_amdgcn_mfma_f32_16x16x32_bf16(ones.v, pF.v, acc_zf, 0, 0, 0);
    acc_zr = __builtin_amdgcn_mfma_f32_16x16x32_bf16(ones.v, pR.v, acc_zr, 0, 0, 0);
#pragma unroll
    for (int dm = 0; dm < 4; dm++) {
      frag_u vf;
      uint2 vv = *(const uint2*)&Vfrag[vbase + (size_t)(kt * 4 + dm) * 256];
      vf.u[0] = vv.x; vf.u[1] = vv.y; vf.u[2] = 0; vf.u[3] = 0;
      accf[dm] = __builtin_amdgcn_mfma_f32_16x16x32_bf16(vf.v, pF.v, accf[dm], 0, 0, 0);
      accr[dm] = __builtin_amdgcn_mfma_f32_16x16x32_bf16(vf.v, pR.v, accr[dm], 0, 0, 0);
    }
  }

  // ---- cross-kh combine (phased through the 32KB red buffer) ----
  if (kh == 1) {
#pragma unroll
    for (int dm = 0; dm < 4; dm++) *(f32x4*)red[qloc][dm][lane] = accf[dm];
    if (lane < 16) { zb[qloc][0][lane] = acc_zf[0]; zb[qloc][1][lane] = acc_zr[0]; }
  }
  __syncthreads();
  if (kh == 0) {
#pragma unroll
    for (int dm = 0; dm < 4; dm++) accf[dm] += *(f32x4*)red[qloc][dm][lane];
  }
  __syncthreads();
  if (kh == 1) {
#pragma unroll
    for (int dm = 0; dm < 4; dm++) *(f32x4*)red[qloc][dm][lane] = accr[dm];
  }
  __syncthreads();
  uint2 outf[4], outr[4];
  if (kh == 0) {
#pragma unroll
    for (int dm = 0; dm < 4; dm++) accr[dm] += *(f32x4*)red[qloc][dm][lane];
    const float zf = acc_zf[0] + zb[qloc][0][c];
    const float zr = acc_zr[0] + zb[qloc][1][c];
    const float izf = 1.0f / zf, izr = 1.0f / zr;
#pragma unroll
    for (int dm = 0; dm < 4; dm++) {
      outf[dm].x = pack_bf16(accf[dm][0] * izf, accf[dm][1] * izf);
      outf[dm].y = pack_bf16(accf[dm][2] * izf, accf[dm][3] * izf);
      outr[dm].x = pack_bf16(accr[dm][0] * izr, accr[dm][1] * izr);
      outr[dm].y = pack_bf16(accr[dm][2] * izr, accr[dm][3] * izr);
    }
  }
  __syncthreads();
  unsigned short* ts = (unsigned short*)red;  // 64 rows x 72 = 9.2 KB < 32 KB
  if (kh == 0) {
    const int qrow = qloc * 16 + c;
#pragma unroll
    for (int dm = 0; dm < 4; dm++) {
      *(uint2*)&ts[qrow * 72 + dm * 16 + quad * 4] = outf[dm];
      *(uint2*)&ts[(32 + qrow) * 72 + dm * 16 + quad * 4] = outr[dm];
    }
  }
  __syncthreads();
  {
    const int row = tid >> 3, seg = tid & 7;
    const size_t g = (size_t)(b * 1024 + qb * 32 + row) * 512 + h * 64 + seg * 8;
    *(uint4*)&Tfb[g] = *(uint4*)&ts[row * 72 + seg * 8];
    *(uint4*)&Trb[g] = *(uint4*)&ts[(32 + row) * 72 + seg * 8];
  }
}

// ---------------------------------------------------------------------------
// Kernel 6: final — LDS-staged fused 4-GEMM + gate combine. grid (8 nb, 64 mt).
// ---------------------------------------------------------------------------
__global__ __launch_bounds__(256, 2) void final_kernel(
    const unsigned short* __restrict__ Tfb, const unsigned short* __restrict__ Trb,
    const unsigned short* __restrict__ wfh, const unsigned short* __restrict__ wfg,
    const unsigned short* __restrict__ wrh, const unsigned short* __restrict__ wrg,
    const float* __restrict__ bfh, const float* __restrict__ bfg,
    const float* __restrict__ brh, const float* __restrict__ brg,
    float* __restrict__ out) {
  __shared__ unsigned short Atf[64 * 64];
  __shared__ unsigned short Atr[64 * 64];
  __shared__ unsigned short Bfh[64 * 64];
  __shared__ unsigned short Bfg[64 * 64];
  __shared__ unsigned short Brh[64 * 64];
  __shared__ unsigned short Brg[64 * 64];
  const int m0 = blockIdx.y * 64, n0 = blockIdx.x * 64;
  const int tid = threadIdx.x, w = tid >> 6, lane = tid & 63;
  const int c = lane & 15, quad = lane >> 4;
  const int wm = w & 1, wn = w >> 1;
  const int rsel = lane >> 3, csel = lane & 7;
  const int sc = csel ^ rsel;
  const char* Agf = (const char*)Tfb + (size_t)(m0 + w * 16 + rsel) * 1024 + sc * 16;
  const char* Agr = (const char*)Trb + (size_t)(m0 + w * 16 + rsel) * 1024 + sc * 16;
  const char* Bg0 = (const char*)wfh + (size_t)(n0 + w * 16 + rsel) * 1024 + sc * 16;
  const char* Bg1 = (const char*)wfg + (size_t)(n0 + w * 16 + rsel) * 1024 + sc * 16;
  const char* Bg2 = (const char*)wrh + (size_t)(n0 + w * 16 + rsel) * 1024 + sc * 16;
  const char* Bg3 = (const char*)wrg + (size_t)(n0 + w * 16 + rsel) * 1024 + sc * 16;
  unsigned short* lAf = &Atf[w * 1024];
  unsigned short* lAr = &Atr[w * 1024];
  unsigned short* l0 = &Bfh[w * 1024];
  unsigned short* l1 = &Bfg[w * 1024];
  unsigned short* l2 = &Brh[w * 1024];
  unsigned short* l3 = &Brg[w * 1024];

  f32x4 acc[4][2][2];
  f32x4 z4 = {0.f, 0.f, 0.f, 0.f};
#pragma unroll
  for (int o = 0; o < 4; o++)
#pragma unroll
    for (int i = 0; i < 2; i++)
#pragma unroll
      for (int j = 0; j < 2; j++) acc[o][i][j] = z4;

  for (int ks = 0; ks < 8; ks++) {
    if (ks) __syncthreads();
    const int kb = ks * 128;
    gload16(Agf + kb, lAf);  gload16(Agf + kb + 8192, lAf + 512);
    gload16(Agr + kb, lAr);  gload16(Agr + kb + 8192, lAr + 512);
    gload16(Bg0 + kb, l0);   gload16(Bg0 + kb + 8192, l0 + 512);
    gload16(Bg1 + kb, l1);   gload16(Bg1 + kb + 8192, l1 + 512);
    gload16(Bg2 + kb, l2);   gload16(Bg2 + kb + 8192, l2 + 512);
    gload16(Bg3 + kb, l3);   gload16(Bg3 + kb + 8192, l3 + 512);
    __syncthreads();
#pragma unroll
    for (int ch = 0; ch < 2; ch++) {
      const int cq = ch * 4 + quad;
      bf16x8 af0 = lds_frag(Atf, wm * 32 + c, cq);
      bf16x8 af1 = lds_frag(Atf, wm * 32 + 16 + c, cq);
      bf16x8 ar0 = lds_frag(Atr, wm * 32 + c, cq);
      bf16x8 ar1 = lds_frag(Atr, wm * 32 + 16 + c, cq);
#pragma unroll
      for (int nt = 0; nt < 2; nt++) {
        const int rb = wn * 32 + nt * 16 + c;
        bf16x8 f0 = lds_frag(Bfh, rb, cq);
        bf16x8 f1 = lds_frag(Bfg, rb, cq);
        bf16x8 f2 = lds_frag(Brh, rb, cq);
        bf16x8 f3 = lds_frag(Brg, rb, cq);
        acc[0][0][nt] = __builtin_amdgcn_mfma_f32_16x16x32_bf16(af0, f0, acc[0][0][nt], 0, 0, 0);
        acc[0][1][nt] = __builtin_amdgcn_mfma_f32_16x16x32_bf16(af1, f0, acc[0][1][nt], 0, 0, 0);
        acc[1][0][nt] = __builtin_amdgcn_mfma_f32_16x16x32_bf16(af0, f1, acc[1][0][nt], 0, 0, 0);
        acc[1][1][nt] = __builtin_amdgcn_mfma_f32_16x16x32_bf16(af1, f1, acc[1][1][nt], 0, 0, 0);
        acc[2][0][nt] = __builtin_amdgcn_mfma_f32_16x16x32_bf16(ar0, f2, acc[2][0][nt], 0, 0, 0);
        acc[2][1][nt] = __builtin_amdgcn_mfma_f32_16x16x32_bf16(ar1, f2, acc[2][1][nt], 0, 0, 0);
        acc[3][0][nt] = __builtin_amdgcn_mfma_f32_16x16x32_bf16(ar0, f3, acc[3][0][nt], 0, 0, 0);
        acc[3][1][nt] = __builtin_amdgcn_mfma_f32_16x16x32_bf16(ar1, f3, acc[3][1][nt], 0, 0, 0);
      }
    }
  }

#pragma unroll
  for (int ms = 0; ms < 2; ms++)
#pragma unroll
    for (int nt = 0; nt < 2; nt++) {
      int n = n0 + wn * 32 + nt * 16 + c;
      float b0 = bfh[n], b1 = bfg[n], b2 = brh[n], b3 = brg[n];
      int t0 = m0 + wm * 32 + ms * 16 + quad * 4;
#pragma unroll
      for (int r = 0; r < 4; r++) {
        int t = t0 + r;
        float Ff = acc[0][ms][nt][r] + b0;
        float Gf = 1.0f / (1.0f + __expf(-(acc[1][ms][nt][r] + b1)));
        float Fr = acc[2][ms][nt][r] + b2;
        float Gr = 1.0f / (1.0f + __expf(-(acc[3][ms][nt][r] + b3)));
        float ef = __expf(Gf), er = __expf(Gr);
        out[(size_t)t * 512 + n] = (Ff * ef + Fr * er) / (ef + er);
      }
    }
}

// ---------------------------------------------------------------------------
// Launch. Workspace (bytes):
//   0: xb 4MB | 4: Qfrag 4MB | 8: Kfrag 4MB | 12: Vfrag 4MB
//   16: Tfb 4MB | 20: Trb 4MB | 24: wt 3.5MB | 28: Mfrag 4MB | 32: Zpart 256KB
// ---------------------------------------------------------------------------
extern "C" void kernel_launch(void* const* d_in, const int* in_sizes, int n_in,
                              void* d_out, int out_size, void* d_ws, size_t ws_size,
                              hipStream_t stream) {
  const float* x   = (const float*)d_in[0];
  const float* Wq  = (const float*)d_in[1];
  const float* bq  = (const float*)d_in[2];
  const float* Wk  = (const float*)d_in[3];
  const float* bk  = (const float*)d_in[4];
  const float* Wv  = (const float*)d_in[5];
  const float* bv  = (const float*)d_in[6];
  const float* cw  = (const float*)d_in[7];
  const float* cb  = (const float*)d_in[8];
  const float* Wfh = (const float*)d_in[9];
  const float* bfh = (const float*)d_in[10];
  const float* Wfg = (const float*)d_in[11];
  const float* bfg = (const float*)d_in[12];
  const float* Wrh = (const float*)d_in[13];
  const float* brh = (const float*)d_in[14];
  const float* Wrg = (const float*)d_in[15];
  const float* brg = (const float*)d_in[16];

  char* ws = (char*)d_ws;
  const size_t MB = 1024 * 1024;
  unsigned short* xb    = (unsigned short*)(ws + 0 * MB);
  unsigned short* Qfrag = (unsigned short*)(ws + 4 * MB);
  unsigned short* Kfrag = (unsigned short*)(ws + 8 * MB);
  unsigned short* Vfrag = (unsigned short*)(ws + 12 * MB);
  unsigned short* Tfb   = (unsigned short*)(ws + 16 * MB);
  unsigned short* Trb   = (unsigned short*)(ws + 20 * MB);
  unsigned short* wt    = (unsigned short*)(ws + 24 * MB);
  unsigned int*   Mfrag = (unsigned int*)(ws + 28 * MB);
  float*          Zpart = (float*)(ws + 32 * MB);
  const size_t WSZ = 512 * 512;

  prep_kernel<<<512, 256, 0, stream>>>(x, Wq, Wk, Wv, Wfh, Wfg, Wrh, Wrg, xb, wt);
  qkv_kernel<<<dim3(8, 64), 256, 0, stream>>>(xb, wt + 0 * WSZ, wt + 1 * WSZ, wt + 2 * WSZ,
                                              bq, bk, bv, Qfrag, Kfrag, Vfrag);
  zpass1_kernel<<<dim3(8, 64), 512, 0, stream>>>(Qfrag, Kfrag, Zpart);
  zpass2_kernel<<<dim3(8, 64), 512, 0, stream>>>(Qfrag, Kfrag, Zpart, cw, cb, Mfrag);
  pv_kernel<<<dim3(8, 128), 256, 0, stream>>>(Qfrag, Kfrag, Vfrag, Mfrag, Zpart, Tfb, Trb);
  final_kernel<<<dim3(8, 64), 256, 0, stream>>>(Tfb, Trb, wt + 3 * WSZ, wt + 4 * WSZ,
                                                wt + 5 * WSZ, wt + 6 * WSZ,
                                                bfh, bfg, brh, brg, (float*)d_out);
}

// Round 7
// 206.675 us; speedup vs baseline: 1.6380x; 1.0444x over previous
//
#include <hip/hip_runtime.h>
#include <hip/hip_bf16.h>
#include <stdint.h>

typedef short bf16x8 __attribute__((ext_vector_type(8)));
typedef float f32x4 __attribute__((ext_vector_type(4)));

__device__ __forceinline__ unsigned short f2bf(float f) {
  union { float f; unsigned int u; } v;
  v.f = f;
  unsigned int u = v.u;
  u = (u + 0x7fffu + ((u >> 16) & 1u)) >> 16;  // RNE
  return (unsigned short)u;
}

__device__ __forceinline__ unsigned int pack_bf16(float x, float y) {
  return (unsigned int)f2bf(x) | ((unsigned int)f2bf(y) << 16);
}

typedef union { bf16x8 v; unsigned int u[4]; } frag_u;

// global->LDS async copy, 16B per lane.
__device__ __forceinline__ void gload16(const void* g, void* lds) {
  __builtin_amdgcn_global_load_lds(
      (const __attribute__((address_space(1))) unsigned int*)(unsigned long long)g,
      (__attribute__((address_space(3))) unsigned int*)(unsigned long long)(unsigned)(unsigned long long)lds,
      16, 0, 0);
}

__device__ __forceinline__ bf16x8 lds_frag(const unsigned short* t, int row, int ch4q) {
  return *(const bf16x8*)(t + row * 64 + ((ch4q ^ (row & 7)) << 3));
}

// Fragment layouts (element = short unless noted):
//  Qfrag/Kfrag[b][t16][h][sub][lane]: ((b*64+t16)*8192) + h*1024 + sub*512 + lane*8
//  Vfrag PAIRED [b][h][ktp][dm][lane][8]: (b*8+h)*65536 + (ktp*4+dm)*512 + lane*8
//        shorts 0..3 = kt=2*ktp, shorts 4..7 = kt=2*ktp+1 (K=32 slot-aligned)
//  Mfrag (u32) PAIRED [b][qt][ktp][lane][2]: (b*64+qt)*4096 + ktp*128 + lane*2 + half

// ---------------------------------------------------------------------------
// Kernel 1: prep — x -> bf16, 7 weights -> transposed bf16 (Wt[n][k] = W[k][n])
// ---------------------------------------------------------------------------
__global__ __launch_bounds__(256) void prep_kernel(
    const float* __restrict__ x,
    const float* __restrict__ Wq, const float* __restrict__ Wk, const float* __restrict__ Wv,
    const float* __restrict__ Wfh, const float* __restrict__ Wfg,
    const float* __restrict__ Wrh, const float* __restrict__ Wrg,
    unsigned short* __restrict__ xb, unsigned short* __restrict__ wt) {
  int bid = blockIdx.x;
  int tid = threadIdx.x;
  if (bid < 448) {
    __shared__ float tile[64][65];
    int mat = bid >> 6;
    int t = bid & 63;
    int tr = (t >> 3) * 64, tc = (t & 7) * 64;
    const float* W = (mat == 0) ? Wq : (mat == 1) ? Wk : (mat == 2) ? Wv
                   : (mat == 3) ? Wfh : (mat == 4) ? Wfg : (mat == 5) ? Wrh : Wrg;
    unsigned short* Wt = wt + (size_t)mat * 512 * 512;
    for (int rep = 0; rep < 16; rep++) {
      int idx = rep * 256 + tid;
      int r = idx >> 6, c = idx & 63;
      tile[r][c] = W[(tr + r) * 512 + tc + c];
    }
    __syncthreads();
    for (int rep = 0; rep < 16; rep++) {
      int idx = rep * 256 + tid;
      int r = idx >> 6, c = idx & 63;
      Wt[(tc + r) * 512 + tr + c] = f2bf(tile[c][r]);
    }
  } else {
    int blk = bid - 448;
    const float4* xi = (const float4*)x;
    for (int rep = 0; rep < 32; rep++) {
      int i = blk * 256 + tid + rep * 16384;
      float4 v = xi[i];
      unsigned int lo = (unsigned int)f2bf(v.x) | ((unsigned int)f2bf(v.y) << 16);
      unsigned int hi = (unsigned int)f2bf(v.z) | ((unsigned int)f2bf(v.w) << 16);
      uint2 u; u.x = lo; u.y = hi;
      *(uint2*)&xb[(size_t)i * 4] = u;
    }
  }
}

// ---------------------------------------------------------------------------
// Kernel 2: QKV projection, LDS-staged GEMM; epilogue emits fragment layouts
// (Qfrag/Kfrag, pair-packed Vfrag). grid (8 nb = head, 64 mt), 256 threads.
// ---------------------------------------------------------------------------
__global__ __launch_bounds__(256, 2) void qkv_kernel(
    const unsigned short* __restrict__ xb,
    const unsigned short* __restrict__ wtq, const unsigned short* __restrict__ wtk,
    const unsigned short* __restrict__ wtv,
    const float* __restrict__ bq, const float* __restrict__ bk, const float* __restrict__ bv,
    unsigned short* __restrict__ Qfrag, unsigned short* __restrict__ Kfrag,
    unsigned short* __restrict__ Vfrag) {
  __shared__ unsigned short As[64 * 64];
  __shared__ unsigned short Bq[64 * 64];
  __shared__ unsigned short Bk[64 * 64];
  __shared__ unsigned short Bv[64 * 64];
  __shared__ __attribute__((aligned(16))) unsigned short st[3][64 * 72];
  const int m0 = blockIdx.y * 64, n0 = blockIdx.x * 64;
  const int tid = threadIdx.x, w = tid >> 6, lane = tid & 63;
  const int c = lane & 15, quad = lane >> 4;
  const int wm = w & 1, wn = w >> 1;
  const int rsel = lane >> 3, csel = lane & 7;
  const int sc = csel ^ rsel;
  const char* Ag  = (const char*)xb  + (size_t)(m0 + w * 16 + rsel) * 1024 + sc * 16;
  const char* Bgq = (const char*)wtq + (size_t)(n0 + w * 16 + rsel) * 1024 + sc * 16;
  const char* Bgk = (const char*)wtk + (size_t)(n0 + w * 16 + rsel) * 1024 + sc * 16;
  const char* Bgv = (const char*)wtv + (size_t)(n0 + w * 16 + rsel) * 1024 + sc * 16;
  unsigned short* lA = &As[w * 1024];
  unsigned short* lQ = &Bq[w * 1024];
  unsigned short* lK = &Bk[w * 1024];
  unsigned short* lV = &Bv[w * 1024];

  f32x4 acc[3][2][2];
  f32x4 z4 = {0.f, 0.f, 0.f, 0.f};
#pragma unroll
  for (int o = 0; o < 3; o++)
#pragma unroll
    for (int i = 0; i < 2; i++)
#pragma unroll
      for (int j = 0; j < 2; j++) acc[o][i][j] = z4;

  for (int ks = 0; ks < 8; ks++) {
    if (ks) __syncthreads();
    const int kb = ks * 128;
    gload16(Ag + kb, lA);        gload16(Ag + kb + 8192, lA + 512);
    gload16(Bgq + kb, lQ);       gload16(Bgq + kb + 8192, lQ + 512);
    gload16(Bgk + kb, lK);       gload16(Bgk + kb + 8192, lK + 512);
    gload16(Bgv + kb, lV);       gload16(Bgv + kb + 8192, lV + 512);
    __syncthreads();
#pragma unroll
    for (int ch = 0; ch < 2; ch++) {
      const int cq = ch * 4 + quad;
      bf16x8 a0 = lds_frag(As, wm * 32 + c, cq);
      bf16x8 a1 = lds_frag(As, wm * 32 + 16 + c, cq);
#pragma unroll
      for (int nt = 0; nt < 2; nt++) {
        const int rb = wn * 32 + nt * 16 + c;
        bf16x8 fq = lds_frag(Bq, rb, cq);
        bf16x8 fk = lds_frag(Bk, rb, cq);
        bf16x8 fv = lds_frag(Bv, rb, cq);
        acc[0][0][nt] = __builtin_amdgcn_mfma_f32_16x16x32_bf16(a0, fq, acc[0][0][nt], 0, 0, 0);
        acc[0][1][nt] = __builtin_amdgcn_mfma_f32_16x16x32_bf16(a1, fq, acc[0][1][nt], 0, 0, 0);
        acc[1][0][nt] = __builtin_amdgcn_mfma_f32_16x16x32_bf16(a0, fk, acc[1][0][nt], 0, 0, 0);
        acc[1][1][nt] = __builtin_amdgcn_mfma_f32_16x16x32_bf16(a1, fk, acc[1][1][nt], 0, 0, 0);
        acc[2][0][nt] = __builtin_amdgcn_mfma_f32_16x16x32_bf16(a0, fv, acc[2][0][nt], 0, 0, 0);
        acc[2][1][nt] = __builtin_amdgcn_mfma_f32_16x16x32_bf16(a1, fv, acc[2][1][nt], 0, 0, 0);
      }
    }
  }

  // stage: st[0]=Q[t][d], st[1]=K[t][d], st[2]=V[d][t]
#pragma unroll
  for (int ms = 0; ms < 2; ms++)
#pragma unroll
    for (int nt = 0; nt < 2; nt++) {
      int n_l = wn * 32 + nt * 16 + c;
      int n = n0 + n_l;
      float biasq = bq[n], biask = bk[n], biasv = bv[n];
#pragma unroll
      for (int r = 0; r < 4; r++) {
        int m_l = wm * 32 + ms * 16 + quad * 4 + r;
        st[0][m_l * 72 + n_l] = f2bf((acc[0][ms][nt][r] + biasq) * 0.125f);
        st[1][m_l * 72 + n_l] = f2bf(acc[1][ms][nt][r] + biask);
        st[2][n_l * 72 + m_l] = f2bf(acc[2][ms][nt][r] + biasv);
      }
    }
  __syncthreads();

  {
    const int h = n0 >> 6;
    const int bb = m0 >> 10, t0b = (m0 & 1023) >> 4;
#pragma unroll
    for (int sub = 0; sub < 2; sub++) {
      uint4 vq = *(uint4*)&st[0][(w * 16 + c) * 72 + sub * 32 + quad * 8];
      uint4 vk = *(uint4*)&st[1][(w * 16 + c) * 72 + sub * 32 + quad * 8];
      size_t base = (size_t)((bb * 64 + t0b + w) * 8192) + h * 1024 + sub * 512 + lane * 8;
      *(uint4*)&Qfrag[base] = vq;
      *(uint4*)&Kfrag[base] = vk;
    }
    // pair-packed V fragments: kt = t0b + w; half = kt&1 selects shorts 0..3/4..7
    const int ktq = t0b + w;
    const int ktp = ktq >> 1, half = ktq & 1;
#pragma unroll
    for (int dm = 0; dm < 4; dm++) {
      uint2 vv = *(uint2*)&st[2][(dm * 16 + c) * 72 + w * 16 + quad * 4];
      size_t base = (size_t)(bb * 8 + h) * 65536 + (size_t)(ktp * 4 + dm) * 512
                  + lane * 8 + half * 4;
      *(uint2*)&Vfrag[base] = vv;
    }
  }
}

// ---------------------------------------------------------------------------
// Kernel 3: zpass1 — partial softmax denominators. grid (8 = b*2+khalf, 64 qt),
// 512 thr (8 waves x 4 kt each = 512 k per block). All loads lane-coalesced.
// ---------------------------------------------------------------------------
__global__ __launch_bounds__(512, 4) void zpass1_kernel(
    const unsigned short* __restrict__ Qfrag, const unsigned short* __restrict__ Kfrag,
    float* __restrict__ Zpart) {
  const int b = blockIdx.x >> 1, khalf = blockIdx.x & 1;
  const int qt = blockIdx.y;
  const int tid = threadIdx.x, w = tid >> 6, lane = tid & 63;
  const int c = lane & 15, quad = lane >> 4;
  __shared__ float zl[8][16];
  if (tid < 128) ((float*)zl)[tid] = 0.f;
  __syncthreads();

  f32x4 z4 = {0.f, 0.f, 0.f, 0.f};
  const size_t qbase = (size_t)((b * 64 + qt) * 8192) + lane * 8;
  bf16x8 qf[8][2];
#pragma unroll
  for (int h = 0; h < 8; h++) {
    qf[h][0] = *(const bf16x8*)&Qfrag[qbase + h * 1024];
    qf[h][1] = *(const bf16x8*)&Qfrag[qbase + h * 1024 + 512];
  }

  float zp[8] = {0, 0, 0, 0, 0, 0, 0, 0};
  for (int i = 0; i < 4; i++) {
    const int kt = khalf * 32 + w * 4 + i;
    const size_t kbase = (size_t)((b * 64 + kt) * 8192) + lane * 8;
#pragma unroll
    for (int h = 0; h < 8; h++) {
      bf16x8 kf0 = *(const bf16x8*)&Kfrag[kbase + h * 1024];
      bf16x8 kf1 = *(const bf16x8*)&Kfrag[kbase + h * 1024 + 512];
      f32x4 s = __builtin_amdgcn_mfma_f32_16x16x32_bf16(kf0, qf[h][0], z4, 0, 0, 0);
      s = __builtin_amdgcn_mfma_f32_16x16x32_bf16(kf1, qf[h][1], s, 0, 0, 0);
      zp[h] += __expf(s[0]) + __expf(s[1]) + __expf(s[2]) + __expf(s[3]);
    }
  }
#pragma unroll
  for (int h = 0; h < 8; h++) {
    float z = zp[h];
    z += __shfl_xor(z, 16); z += __shfl_xor(z, 32);
    if (quad == 0) atomicAdd(&zl[h][c], z);
  }
  __syncthreads();
  if (tid < 128) {
    int h = tid >> 4, q = tid & 15;
    Zpart[(size_t)((b * 64 + qt) * 8 + h) * 32 + khalf * 16 + q] = zl[h][q];
  }
}

// ---------------------------------------------------------------------------
// Kernel 4: zpass2 — gate + mask bytes (pair-packed Mfrag). Same grid;
// ZERO LDS, ZERO barriers. cw[h]*invZ[h] folded into one constant per head.
// ---------------------------------------------------------------------------
__global__ __launch_bounds__(512, 4) void zpass2_kernel(
    const unsigned short* __restrict__ Qfrag, const unsigned short* __restrict__ Kfrag,
    const float* __restrict__ Zpart,
    const float* __restrict__ conv_w, const float* __restrict__ conv_b,
    unsigned int* __restrict__ Mfrag) {
  const int b = blockIdx.x >> 1, khalf = blockIdx.x & 1;
  const int qt = blockIdx.y;
  const int tid = threadIdx.x, w = tid >> 6, lane = tid & 63;
  const int c = lane & 15;

  f32x4 z4 = {0.f, 0.f, 0.f, 0.f};
  const float cb = conv_b[0];
  float cwz[8];
#pragma unroll
  for (int h = 0; h < 8; h++) {
    const float* zp = &Zpart[(size_t)((b * 64 + qt) * 8 + h) * 32];
    cwz[h] = conv_w[h] / (zp[c] + zp[16 + c]);
  }

  const size_t qbase = (size_t)((b * 64 + qt) * 8192) + lane * 8;
  bf16x8 qf[8][2];
#pragma unroll
  for (int h = 0; h < 8; h++) {
    qf[h][0] = *(const bf16x8*)&Qfrag[qbase + h * 1024];
    qf[h][1] = *(const bf16x8*)&Qfrag[qbase + h * 1024 + 512];
  }

  for (int i = 0; i < 4; i++) {
    const int kt = khalf * 32 + w * 4 + i;
    const size_t kbase = (size_t)((b * 64 + kt) * 8192) + lane * 8;
    f32x4 zc = {cb, cb, cb, cb};
#pragma unroll
    for (int h = 0; h < 8; h++) {
      bf16x8 kf0 = *(const bf16x8*)&Kfrag[kbase + h * 1024];
      bf16x8 kf1 = *(const bf16x8*)&Kfrag[kbase + h * 1024 + 512];
      f32x4 s = __builtin_amdgcn_mfma_f32_16x16x32_bf16(kf0, qf[h][0], z4, 0, 0, 0);
      s = __builtin_amdgcn_mfma_f32_16x16x32_bf16(kf1, qf[h][1], s, 0, 0, 0);
      zc[0] += cwz[h] * __expf(s[0]);
      zc[1] += cwz[h] * __expf(s[1]);
      zc[2] += cwz[h] * __expf(s[2]);
      zc[3] += cwz[h] * __expf(s[3]);
    }
    unsigned int packed = 0;
#pragma unroll
    for (int r = 0; r < 4; r++) {
      unsigned int m = (zc[r] <= 0.f ? 1u : 0u) | (zc[r] >= 0.f ? 2u : 0u);
      packed |= m << (8 * r);
    }
    Mfrag[(size_t)(b * 64 + qt) * 4096 + (kt >> 1) * 128 + lane * 2 + (kt & 1)] = packed;
  }
}

// ---------------------------------------------------------------------------
// Kernel 5: pv — grid (8 h, 128 = b*32+qb), 256 thr = 4 waves =
// (2 q-tiles x 2 k-halves) -> 4 blocks/CU, 16 waves/CU. Pair-packed K=32
// MFMAs (P and V fill all 8 slots); denominators via ones-row MFMA; phased
// LDS combine in the epilogue. Barrier-free main loop.
// ---------------------------------------------------------------------------
__global__ __launch_bounds__(256, 4) void pv_kernel(
    const unsigned short* __restrict__ Qfrag, const unsigned short* __restrict__ Kfrag,
    const unsigned short* __restrict__ Vfrag,
    const unsigned int* __restrict__ Mfrag, const float* __restrict__ Zpart,
    unsigned short* __restrict__ Tfb, unsigned short* __restrict__ Trb) {
  const int h = blockIdx.x;
  const int b = blockIdx.y >> 5, qb = blockIdx.y & 31;
  const int tid = threadIdx.x, w = tid >> 6, lane = tid & 63;
  const int c = lane & 15, quad = lane >> 4;
  const int qloc = w & 1, kh = w >> 1;
  const int qt = qb * 2 + qloc;

  __shared__ __attribute__((aligned(16))) float red[2][4][256][4];  // 32 KB, reused
  __shared__ float zb[2][2][16];

  f32x4 z4 = {0.f, 0.f, 0.f, 0.f};
  const size_t qbase = (size_t)((b * 64 + qt) * 8192) + h * 1024 + lane * 8;
  bf16x8 qf0 = *(const bf16x8*)&Qfrag[qbase];
  bf16x8 qf1 = *(const bf16x8*)&Qfrag[qbase + 512];
  const float* zpp = &Zpart[(size_t)((b * 64 + qt) * 8 + h) * 32];
  const float invZ = 1.0f / (zpp[c] + zpp[16 + c]);
  const size_t mbase = (size_t)(b * 64 + qt) * 4096 + lane * 2;
  const size_t vb0 = (size_t)(b * 8 + h) * 65536 + lane * 8;

  frag_u ones;
  ones.u[0] = 0x3F803F80u; ones.u[1] = 0x3F803F80u;
  ones.u[2] = 0x3F803F80u; ones.u[3] = 0x3F803F80u;

  f32x4 accf[4], accr[4];
#pragma unroll
  for (int i = 0; i < 4; i++) { accf[i] = z4; accr[i] = z4; }
  f32x4 acc_zf = z4, acc_zr = z4;

#pragma unroll 2
  for (int ip = 0; ip < 16; ip++) {
    const int ktp = kh * 16 + ip;
    const int kta = ktp * 2, ktb = kta + 1;
    const size_t kba = (size_t)((b * 64 + kta) * 8192) + h * 1024 + lane * 8;
    const size_t kbb = (size_t)((b * 64 + ktb) * 8192) + h * 1024 + lane * 8;
    bf16x8 ka0 = *(const bf16x8*)&Kfrag[kba];
    bf16x8 ka1 = *(const bf16x8*)&Kfrag[kba + 512];
    bf16x8 kb0 = *(const bf16x8*)&Kfrag[kbb];
    bf16x8 kb1 = *(const bf16x8*)&Kfrag[kbb + 512];
    f32x4 sa = __builtin_amdgcn_mfma_f32_16x16x32_bf16(ka0, qf0, z4, 0, 0, 0);
    sa = __builtin_amdgcn_mfma_f32_16x16x32_bf16(ka1, qf1, sa, 0, 0, 0);
    f32x4 sb = __builtin_amdgcn_mfma_f32_16x16x32_bf16(kb0, qf0, z4, 0, 0, 0);
    sb = __builtin_amdgcn_mfma_f32_16x16x32_bf16(kb1, qf1, sb, 0, 0, 0);
    const uint2 mp = *(const uint2*)&Mfrag[mbase + (size_t)ktp * 128];
    float ea[4], eb[4];
#pragma unroll
    for (int r = 0; r < 4; r++) {
      ea[r] = __expf(__expf(sa[r]) * invZ);
      eb[r] = __expf(__expf(sb[r]) * invZ);
    }
    frag_u pF, pR;
    pF.u[0] = pack_bf16((mp.x & 0x1u) ? ea[0] : 1.f, (mp.x & 0x100u) ? ea[1] : 1.f);
    pF.u[1] = pack_bf16((mp.x & 0x10000u) ? ea[2] : 1.f, (mp.x & 0x1000000u) ? ea[3] : 1.f);
    pF.u[2] = pack_bf16((mp.y & 0x1u) ? eb[0] : 1.f, (mp.y & 0x100u) ? eb[1] : 1.f);
    pF.u[3] = pack_bf16((mp.y & 0x10000u) ? eb[2] : 1.f, (mp.y & 0x1000000u) ? eb[3] : 1.f);
    pR.u[0] = pack_bf16((mp.x & 0x2u) ? ea[0] : 1.f, (mp.x & 0x200u) ? ea[1] : 1.f);
    pR.u[1] = pack_bf16((mp.x & 0x20000u) ? ea[2] : 1.f, (mp.x & 0x2000000u) ? ea[3] : 1.f);
    pR.u[2] = pack_bf16((mp.y & 0x2u) ? eb[0] : 1.f, (mp.y & 0x200u) ? eb[1] : 1.f);
    pR.u[3] = pack_bf16((mp.y & 0x20000u) ? eb[2] : 1.f, (mp.y & 0x2000000u) ? eb[3] : 1.f);
    acc_zf = __builtin_amdgcn_mfma_f32_16x16x32_bf16(ones.v, pF.v, acc_zf, 0, 0, 0);
    acc_zr = __builtin_amdgcn_mfma_f32_16x16x32_bf16(ones.v, pR.v, acc_zr, 0, 0, 0);
#pragma unroll
    for (int dm = 0; dm < 4; dm++) {
      bf16x8 vf = *(const bf16x8*)&Vfrag[vb0 + (size_t)(ktp * 4 + dm) * 512];
      accf[dm] = __builtin_amdgcn_mfma_f32_16x16x32_bf16(vf, pF.v, accf[dm], 0, 0, 0);
      accr[dm] = __builtin_amdgcn_mfma_f32_16x16x32_bf16(vf, pR.v, accr[dm], 0, 0, 0);
    }
  }

  // ---- cross-kh combine (phased through the 32KB red buffer) ----
  if (kh == 1) {
#pragma unroll
    for (int dm = 0; dm < 4; dm++) *(f32x4*)red[qloc][dm][lane] = accf[dm];
    if (lane < 16) { zb[qloc][0][lane] = acc_zf[0]; zb[qloc][1][lane] = acc_zr[0]; }
  }
  __syncthreads();
  if (kh == 0) {
#pragma unroll
    for (int dm = 0; dm < 4; dm++) accf[dm] += *(f32x4*)red[qloc][dm][lane];
  }
  __syncthreads();
  if (kh == 1) {
#pragma unroll
    for (int dm = 0; dm < 4; dm++) *(f32x4*)red[qloc][dm][lane] = accr[dm];
  }
  __syncthreads();
  uint2 outf[4], outr[4];
  if (kh == 0) {
#pragma unroll
    for (int dm = 0; dm < 4; dm++) accr[dm] += *(f32x4*)red[qloc][dm][lane];
    const float zf = acc_zf[0] + zb[qloc][0][c];
    const float zr = acc_zr[0] + zb[qloc][1][c];
    const float izf = 1.0f / zf, izr = 1.0f / zr;
#pragma unroll
    for (int dm = 0; dm < 4; dm++) {
      outf[dm].x = pack_bf16(accf[dm][0] * izf, accf[dm][1] * izf);
      outf[dm].y = pack_bf16(accf[dm][2] * izf, accf[dm][3] * izf);
      outr[dm].x = pack_bf16(accr[dm][0] * izr, accr[dm][1] * izr);
      outr[dm].y = pack_bf16(accr[dm][2] * izr, accr[dm][3] * izr);
    }
  }
  __syncthreads();
  unsigned short* ts = (unsigned short*)red;  // 64 rows x 72 = 9.2 KB < 32 KB
  if (kh == 0) {
    const int qrow = qloc * 16 + c;
#pragma unroll
    for (int dm = 0; dm < 4; dm++) {
      *(uint2*)&ts[qrow * 72 + dm * 16 + quad * 4] = outf[dm];
      *(uint2*)&ts[(32 + qrow) * 72 + dm * 16 + quad * 4] = outr[dm];
    }
  }
  __syncthreads();
  {
    const int row = tid >> 3, seg = tid & 7;
    const size_t g = (size_t)(b * 1024 + qb * 32 + row) * 512 + h * 64 + seg * 8;
    *(uint4*)&Tfb[g] = *(uint4*)&ts[row * 72 + seg * 8];
    *(uint4*)&Trb[g] = *(uint4*)&ts[(32 + row) * 72 + seg * 8];
  }
}

// ---------------------------------------------------------------------------
// Kernel 6: final — LDS-staged fused 4-GEMM + gate combine. grid (8 nb, 64 mt).
// 48 KB LDS -> 3 blocks/CU.
// ---------------------------------------------------------------------------
__global__ __launch_bounds__(256, 3) void final_kernel(
    const unsigned short* __restrict__ Tfb, const unsigned short* __restrict__ Trb,
    const unsigned short* __restrict__ wfh, const unsigned short* __restrict__ wfg,
    const unsigned short* __restrict__ wrh, const unsigned short* __restrict__ wrg,
    const float* __restrict__ bfh, const float* __restrict__ bfg,
    const float* __restrict__ brh, const float* __restrict__ brg,
    float* __restrict__ out) {
  __shared__ unsigned short Atf[64 * 64];
  __shared__ unsigned short Atr[64 * 64];
  __shared__ unsigned short Bfh[64 * 64];
  __shared__ unsigned short Bfg[64 * 64];
  __shared__ unsigned short Brh[64 * 64];
  __shared__ unsigned short Brg[64 * 64];
  const int m0 = blockIdx.y * 64, n0 = blockIdx.x * 64;
  const int tid = threadIdx.x, w = tid >> 6, lane = tid & 63;
  const int c = lane & 15, quad = lane >> 4;
  const int wm = w & 1, wn = w >> 1;
  const int rsel = lane >> 3, csel = lane & 7;
  const int sc = csel ^ rsel;
  const char* Agf = (const char*)Tfb + (size_t)(m0 + w * 16 + rsel) * 1024 + sc * 16;
  const char* Agr = (const char*)Trb + (size_t)(m0 + w * 16 + rsel) * 1024 + sc * 16;
  const char* Bg0 = (const char*)wfh + (size_t)(n0 + w * 16 + rsel) * 1024 + sc * 16;
  const char* Bg1 = (const char*)wfg + (size_t)(n0 + w * 16 + rsel) * 1024 + sc * 16;
  const char* Bg2 = (const char*)wrh + (size_t)(n0 + w * 16 + rsel) * 1024 + sc * 16;
  const char* Bg3 = (const char*)wrg + (size_t)(n0 + w * 16 + rsel) * 1024 + sc * 16;
  unsigned short* lAf = &Atf[w * 1024];
  unsigned short* lAr = &Atr[w * 1024];
  unsigned short* l0 = &Bfh[w * 1024];
  unsigned short* l1 = &Bfg[w * 1024];
  unsigned short* l2 = &Brh[w * 1024];
  unsigned short* l3 = &Brg[w * 1024];

  f32x4 acc[4][2][2];
  f32x4 z4 = {0.f, 0.f, 0.f, 0.f};
#pragma unroll
  for (int o = 0; o < 4; o++)
#pragma unroll
    for (int i = 0; i < 2; i++)
#pragma unroll
      for (int j = 0; j < 2; j++) acc[o][i][j] = z4;

  for (int ks = 0; ks < 8; ks++) {
    if (ks) __syncthreads();
    const int kb = ks * 128;
    gload16(Agf + kb, lAf);  gload16(Agf + kb + 8192, lAf + 512);
    gload16(Agr + kb, lAr);  gload16(Agr + kb + 8192, lAr + 512);
    gload16(Bg0 + kb, l0);   gload16(Bg0 + kb + 8192, l0 + 512);
    gload16(Bg1 + kb, l1);   gload16(Bg1 + kb + 8192, l1 + 512);
    gload16(Bg2 + kb, l2);   gload16(Bg2 + kb + 8192, l2 + 512);
    gload16(Bg3 + kb, l3);   gload16(Bg3 + kb + 8192, l3 + 512);
    __syncthreads();
#pragma unroll
    for (int ch = 0; ch < 2; ch++) {
      const int cq = ch * 4 + quad;
      bf16x8 af0 = lds_frag(Atf, wm * 32 + c, cq);
      bf16x8 af1 = lds_frag(Atf, wm * 32 + 16 + c, cq);
      bf16x8 ar0 = lds_frag(Atr, wm * 32 + c, cq);
      bf16x8 ar1 = lds_frag(Atr, wm * 32 + 16 + c, cq);
#pragma unroll
      for (int nt = 0; nt < 2; nt++) {
        const int rb = wn * 32 + nt * 16 + c;
        bf16x8 f0 = lds_frag(Bfh, rb, cq);
        bf16x8 f1 = lds_frag(Bfg, rb, cq);
        bf16x8 f2 = lds_frag(Brh, rb, cq);
        bf16x8 f3 = lds_frag(Brg, rb, cq);
        acc[0][0][nt] = __builtin_amdgcn_mfma_f32_16x16x32_bf16(af0, f0, acc[0][0][nt], 0, 0, 0);
        acc[0][1][nt] = __builtin_amdgcn_mfma_f32_16x16x32_bf16(af1, f0, acc[0][1][nt], 0, 0, 0);
        acc[1][0][nt] = __builtin_amdgcn_mfma_f32_16x16x32_bf16(af0, f1, acc[1][0][nt], 0, 0, 0);
        acc[1][1][nt] = __builtin_amdgcn_mfma_f32_16x16x32_bf16(af1, f1, acc[1][1][nt], 0, 0, 0);
        acc[2][0][nt] = __builtin_amdgcn_mfma_f32_16x16x32_bf16(ar0, f2, acc[2][0][nt], 0, 0, 0);
        acc[2][1][nt] = __builtin_amdgcn_mfma_f32_16x16x32_bf16(ar1, f2, acc[2][1][nt], 0, 0, 0);
        acc[3][0][nt] = __builtin_amdgcn_mfma_f32_16x16x32_bf16(ar0, f3, acc[3][0][nt], 0, 0, 0);
        acc[3][1][nt] = __builtin_amdgcn_mfma_f32_16x16x32_bf16(ar1, f3, acc[3][1][nt], 0, 0, 0);
      }
    }
  }

#pragma unroll
  for (int ms = 0; ms < 2; ms++)
#pragma unroll
    for (int nt = 0; nt < 2; nt++) {
      int n = n0 + wn * 32 + nt * 16 + c;
      float b0 = bfh[n], b1 = bfg[n], b2 = brh[n], b3 = brg[n];
      int t0 = m0 + wm * 32 + ms * 16 + quad * 4;
#pragma unroll
      for (int r = 0; r < 4; r++) {
        int t = t0 + r;
        float Ff = acc[0][ms][nt][r] + b0;
        float Gf = 1.0f / (1.0f + __expf(-(acc[1][ms][nt][r] + b1)));
        float Fr = acc[2][ms][nt][r] + b2;
        float Gr = 1.0f / (1.0f + __expf(-(acc[3][ms][nt][r] + b3)));
        float ef = __expf(Gf), er = __expf(Gr);
        out[(size_t)t * 512 + n] = (Ff * ef + Fr * er) / (ef + er);
      }
    }
}

// ---------------------------------------------------------------------------
// Launch. Workspace (bytes):
//   0: xb 4MB | 4: Qfrag 4MB | 8: Kfrag 4MB | 12: Vfrag 4MB
//   16: Tfb 4MB | 20: Trb 4MB | 24: wt 3.5MB | 28: Mfrag 4MB | 32: Zpart 256KB
// ---------------------------------------------------------------------------
extern "C" void kernel_launch(void* const* d_in, const int* in_sizes, int n_in,
                              void* d_out, int out_size, void* d_ws, size_t ws_size,
                              hipStream_t stream) {
  const float* x   = (const float*)d_in[0];
  const float* Wq  = (const float*)d_in[1];
  const float* bq  = (const float*)d_in[2];
  const float* Wk  = (const float*)d_in[3];
  const float* bk  = (const float*)d_in[4];
  const float* Wv  = (const float*)d_in[5];
  const float* bv  = (const float*)d_in[6];
  const float* cw  = (const float*)d_in[7];
  const float* cb  = (const float*)d_in[8];
  const float* Wfh = (const float*)d_in[9];
  const float* bfh = (const float*)d_in[10];
  const float* Wfg = (const float*)d_in[11];
  const float* bfg = (const float*)d_in[12];
  const float* Wrh = (const float*)d_in[13];
  const float* brh = (const float*)d_in[14];
  const float* Wrg = (const float*)d_in[15];
  const float* brg = (const float*)d_in[16];

  char* ws = (char*)d_ws;
  const size_t MB = 1024 * 1024;
  unsigned short* xb    = (unsigned short*)(ws + 0 * MB);
  unsigned short* Qfrag = (unsigned short*)(ws + 4 * MB);
  unsigned short* Kfrag = (unsigned short*)(ws + 8 * MB);
  unsigned short* Vfrag = (unsigned short*)(ws + 12 * MB);
  unsigned short* Tfb   = (unsigned short*)(ws + 16 * MB);
  unsigned short* Trb   = (unsigned short*)(ws + 20 * MB);
  unsigned short* wt    = (unsigned short*)(ws + 24 * MB);
  unsigned int*   Mfrag = (unsigned int*)(ws + 28 * MB);
  float*          Zpart = (float*)(ws + 32 * MB);
  const size_t WSZ = 512 * 512;

  prep_kernel<<<512, 256, 0, stream>>>(x, Wq, Wk, Wv, Wfh, Wfg, Wrh, Wrg, xb, wt);
  qkv_kernel<<<dim3(8, 64), 256, 0, stream>>>(xb, wt + 0 * WSZ, wt + 1 * WSZ, wt + 2 * WSZ,
                                              bq, bk, bv, Qfrag, Kfrag, Vfrag);
  zpass1_kernel<<<dim3(8, 64), 512, 0, stream>>>(Qfrag, Kfrag, Zpart);
  zpass2_kernel<<<dim3(8, 64), 512, 0, stream>>>(Qfrag, Kfrag, Zpart, cw, cb, Mfrag);
  pv_kernel<<<dim3(8, 128), 256, 0, stream>>>(Qfrag, Kfrag, Vfrag, Mfrag, Zpart, Tfb, Trb);
  final_kernel<<<dim3(8, 64), 256, 0, stream>>>(Tfb, Trb, wt + 3 * WSZ, wt + 4 * WSZ,
                                                wt + 5 * WSZ, wt + 6 * WSZ,
                                                bfh, bfg, brh, brg, (float*)d_out);
}

// Round 8
// 194.159 us; speedup vs baseline: 1.7436x; 1.0645x over previous
//
#include <hip/hip_runtime.h>
#include <hip/hip_bf16.h>
#include <stdint.h>

typedef short bf16x8 __attribute__((ext_vector_type(8)));
typedef float f32x4 __attribute__((ext_vector_type(4)));

__device__ __forceinline__ unsigned short f2bf(float f) {
  union { float f; unsigned int u; } v;
  v.f = f;
  unsigned int u = v.u;
  u = (u + 0x7fffu + ((u >> 16) & 1u)) >> 16;  // RNE
  return (unsigned short)u;
}

__device__ __forceinline__ unsigned int pack_bf16(float x, float y) {
  return (unsigned int)f2bf(x) | ((unsigned int)f2bf(y) << 16);
}

typedef union { bf16x8 v; unsigned int u[4]; } frag_u;

// global->LDS async copy, 16B per lane.
__device__ __forceinline__ void gload16(const void* g, void* lds) {
  __builtin_amdgcn_global_load_lds(
      (const __attribute__((address_space(1))) unsigned int*)(unsigned long long)g,
      (__attribute__((address_space(3))) unsigned int*)(unsigned long long)(unsigned)(unsigned long long)lds,
      16, 0, 0);
}

__device__ __forceinline__ bf16x8 lds_frag(const unsigned short* t, int row, int ch4q) {
  return *(const bf16x8*)(t + row * 64 + ((ch4q ^ (row & 7)) << 3));
}

// Fragment layouts (element = short unless noted):
//  Qfrag/Kfrag[b][t16][h][sub][lane]: ((b*64+t16)*8192) + h*1024 + sub*512 + lane*8
//  Vfrag PAIRED [b][h][ktp][dm][lane][8]: (b*8+h)*65536 + (ktp*4+dm)*512 + lane*8
//  Mfrag (u32) PAIRED [b][qt][ktp][lane][2]: (b*64+qt)*4096 + ktp*128 + lane*2 + half
//  Zpart [b][qt][h][kq*16+q]: ((b*64+qt)*8+h)*64 + kq*16 + q   (4 k-quarters)

// ---------------------------------------------------------------------------
// Kernel 1: prep — x -> bf16, 7 weights -> transposed bf16 (Wt[n][k] = W[k][n])
// ---------------------------------------------------------------------------
__global__ __launch_bounds__(256) void prep_kernel(
    const float* __restrict__ x,
    const float* __restrict__ Wq, const float* __restrict__ Wk, const float* __restrict__ Wv,
    const float* __restrict__ Wfh, const float* __restrict__ Wfg,
    const float* __restrict__ Wrh, const float* __restrict__ Wrg,
    unsigned short* __restrict__ xb, unsigned short* __restrict__ wt) {
  int bid = blockIdx.x;
  int tid = threadIdx.x;
  if (bid < 448) {
    __shared__ float tile[64][65];
    int mat = bid >> 6;
    int t = bid & 63;
    int tr = (t >> 3) * 64, tc = (t & 7) * 64;
    const float* W = (mat == 0) ? Wq : (mat == 1) ? Wk : (mat == 2) ? Wv
                   : (mat == 3) ? Wfh : (mat == 4) ? Wfg : (mat == 5) ? Wrh : Wrg;
    unsigned short* Wt = wt + (size_t)mat * 512 * 512;
    for (int rep = 0; rep < 16; rep++) {
      int idx = rep * 256 + tid;
      int r = idx >> 6, c = idx & 63;
      tile[r][c] = W[(tr + r) * 512 + tc + c];
    }
    __syncthreads();
    for (int rep = 0; rep < 16; rep++) {
      int idx = rep * 256 + tid;
      int r = idx >> 6, c = idx & 63;
      Wt[(tc + r) * 512 + tr + c] = f2bf(tile[c][r]);
    }
  } else {
    int blk = bid - 448;
    const float4* xi = (const float4*)x;
    for (int rep = 0; rep < 32; rep++) {
      int i = blk * 256 + tid + rep * 16384;
      float4 v = xi[i];
      unsigned int lo = (unsigned int)f2bf(v.x) | ((unsigned int)f2bf(v.y) << 16);
      unsigned int hi = (unsigned int)f2bf(v.z) | ((unsigned int)f2bf(v.w) << 16);
      uint2 u; u.x = lo; u.y = hi;
      *(uint2*)&xb[(size_t)i * 4] = u;
    }
  }
}

// ---------------------------------------------------------------------------
// Kernel 2: QKV projection, LDS-staged GEMM; epilogue emits fragment layouts
// (Qfrag/Kfrag, pair-packed Vfrag). grid (8 nb = head, 64 mt), 256 threads.
// ---------------------------------------------------------------------------
__global__ __launch_bounds__(256, 2) void qkv_kernel(
    const unsigned short* __restrict__ xb,
    const unsigned short* __restrict__ wtq, const unsigned short* __restrict__ wtk,
    const unsigned short* __restrict__ wtv,
    const float* __restrict__ bq, const float* __restrict__ bk, const float* __restrict__ bv,
    unsigned short* __restrict__ Qfrag, unsigned short* __restrict__ Kfrag,
    unsigned short* __restrict__ Vfrag) {
  __shared__ unsigned short As[64 * 64];
  __shared__ unsigned short Bq[64 * 64];
  __shared__ unsigned short Bk[64 * 64];
  __shared__ unsigned short Bv[64 * 64];
  __shared__ __attribute__((aligned(16))) unsigned short st[3][64 * 72];
  const int m0 = blockIdx.y * 64, n0 = blockIdx.x * 64;
  const int tid = threadIdx.x, w = tid >> 6, lane = tid & 63;
  const int c = lane & 15, quad = lane >> 4;
  const int wm = w & 1, wn = w >> 1;
  const int rsel = lane >> 3, csel = lane & 7;
  const int sc = csel ^ rsel;
  const char* Ag  = (const char*)xb  + (size_t)(m0 + w * 16 + rsel) * 1024 + sc * 16;
  const char* Bgq = (const char*)wtq + (size_t)(n0 + w * 16 + rsel) * 1024 + sc * 16;
  const char* Bgk = (const char*)wtk + (size_t)(n0 + w * 16 + rsel) * 1024 + sc * 16;
  const char* Bgv = (const char*)wtv + (size_t)(n0 + w * 16 + rsel) * 1024 + sc * 16;
  unsigned short* lA = &As[w * 1024];
  unsigned short* lQ = &Bq[w * 1024];
  unsigned short* lK = &Bk[w * 1024];
  unsigned short* lV = &Bv[w * 1024];

  f32x4 acc[3][2][2];
  f32x4 z4 = {0.f, 0.f, 0.f, 0.f};
#pragma unroll
  for (int o = 0; o < 3; o++)
#pragma unroll
    for (int i = 0; i < 2; i++)
#pragma unroll
      for (int j = 0; j < 2; j++) acc[o][i][j] = z4;

  for (int ks = 0; ks < 8; ks++) {
    if (ks) __syncthreads();
    const int kb = ks * 128;
    gload16(Ag + kb, lA);        gload16(Ag + kb + 8192, lA + 512);
    gload16(Bgq + kb, lQ);       gload16(Bgq + kb + 8192, lQ + 512);
    gload16(Bgk + kb, lK);       gload16(Bgk + kb + 8192, lK + 512);
    gload16(Bgv + kb, lV);       gload16(Bgv + kb + 8192, lV + 512);
    __syncthreads();
#pragma unroll
    for (int ch = 0; ch < 2; ch++) {
      const int cq = ch * 4 + quad;
      bf16x8 a0 = lds_frag(As, wm * 32 + c, cq);
      bf16x8 a1 = lds_frag(As, wm * 32 + 16 + c, cq);
#pragma unroll
      for (int nt = 0; nt < 2; nt++) {
        const int rb = wn * 32 + nt * 16 + c;
        bf16x8 fq = lds_frag(Bq, rb, cq);
        bf16x8 fk = lds_frag(Bk, rb, cq);
        bf16x8 fv = lds_frag(Bv, rb, cq);
        acc[0][0][nt] = __builtin_amdgcn_mfma_f32_16x16x32_bf16(a0, fq, acc[0][0][nt], 0, 0, 0);
        acc[0][1][nt] = __builtin_amdgcn_mfma_f32_16x16x32_bf16(a1, fq, acc[0][1][nt], 0, 0, 0);
        acc[1][0][nt] = __builtin_amdgcn_mfma_f32_16x16x32_bf16(a0, fk, acc[1][0][nt], 0, 0, 0);
        acc[1][1][nt] = __builtin_amdgcn_mfma_f32_16x16x32_bf16(a1, fk, acc[1][1][nt], 0, 0, 0);
        acc[2][0][nt] = __builtin_amdgcn_mfma_f32_16x16x32_bf16(a0, fv, acc[2][0][nt], 0, 0, 0);
        acc[2][1][nt] = __builtin_amdgcn_mfma_f32_16x16x32_bf16(a1, fv, acc[2][1][nt], 0, 0, 0);
      }
    }
  }

  // stage: st[0]=Q[t][d], st[1]=K[t][d], st[2]=V[d][t]
#pragma unroll
  for (int ms = 0; ms < 2; ms++)
#pragma unroll
    for (int nt = 0; nt < 2; nt++) {
      int n_l = wn * 32 + nt * 16 + c;
      int n = n0 + n_l;
      float biasq = bq[n], biask = bk[n], biasv = bv[n];
#pragma unroll
      for (int r = 0; r < 4; r++) {
        int m_l = wm * 32 + ms * 16 + quad * 4 + r;
        st[0][m_l * 72 + n_l] = f2bf((acc[0][ms][nt][r] + biasq) * 0.125f);
        st[1][m_l * 72 + n_l] = f2bf(acc[1][ms][nt][r] + biask);
        st[2][n_l * 72 + m_l] = f2bf(acc[2][ms][nt][r] + biasv);
      }
    }
  __syncthreads();

  {
    const int h = n0 >> 6;
    const int bb = m0 >> 10, t0b = (m0 & 1023) >> 4;
#pragma unroll
    for (int sub = 0; sub < 2; sub++) {
      uint4 vq = *(uint4*)&st[0][(w * 16 + c) * 72 + sub * 32 + quad * 8];
      uint4 vk = *(uint4*)&st[1][(w * 16 + c) * 72 + sub * 32 + quad * 8];
      size_t base = (size_t)((bb * 64 + t0b + w) * 8192) + h * 1024 + sub * 512 + lane * 8;
      *(uint4*)&Qfrag[base] = vq;
      *(uint4*)&Kfrag[base] = vk;
    }
    // pair-packed V fragments: kt = t0b + w; half = kt&1 selects shorts 0..3/4..7
    const int ktq = t0b + w;
    const int ktp = ktq >> 1, half = ktq & 1;
#pragma unroll
    for (int dm = 0; dm < 4; dm++) {
      uint2 vv = *(uint2*)&st[2][(dm * 16 + c) * 72 + w * 16 + quad * 4];
      size_t base = (size_t)(bb * 8 + h) * 65536 + (size_t)(ktp * 4 + dm) * 512
                  + lane * 8 + half * 4;
      *(uint2*)&Vfrag[base] = vv;
    }
  }
}

// ---------------------------------------------------------------------------
// Kernel 3: zpass1 — partial softmax denominators. grid (16 = b*4+kq, 64 qt),
// 512 thr, h-outer loop (low VGPR) -> (512,8) = 32 waves/CU, 4 blocks/CU.
// Wave handles 2 consecutive kt (32 k).
// ---------------------------------------------------------------------------
__global__ __launch_bounds__(512, 8) void zpass1_kernel(
    const unsigned short* __restrict__ Qfrag, const unsigned short* __restrict__ Kfrag,
    float* __restrict__ Zpart) {
  const int b = blockIdx.x >> 2, kq = blockIdx.x & 3;
  const int qt = blockIdx.y;
  const int tid = threadIdx.x, w = tid >> 6, lane = tid & 63;
  const int c = lane & 15, quad = lane >> 4;
  __shared__ float zl[8][16];
  if (tid < 128) ((float*)zl)[tid] = 0.f;
  __syncthreads();

  f32x4 z4 = {0.f, 0.f, 0.f, 0.f};
  const size_t qbase = (size_t)((b * 64 + qt) * 8192) + lane * 8;
  const int kt0 = kq * 16 + w * 2;
  const size_t kb0 = (size_t)((b * 64 + kt0) * 8192) + lane * 8;

  for (int h = 0; h < 8; h++) {
    bf16x8 qf0 = *(const bf16x8*)&Qfrag[qbase + h * 1024];
    bf16x8 qf1 = *(const bf16x8*)&Qfrag[qbase + h * 1024 + 512];
    float zh = 0.f;
#pragma unroll
    for (int i = 0; i < 2; i++) {
      const size_t kb = kb0 + (size_t)i * 8192 + h * 1024;
      bf16x8 kf0 = *(const bf16x8*)&Kfrag[kb];
      bf16x8 kf1 = *(const bf16x8*)&Kfrag[kb + 512];
      f32x4 s = __builtin_amdgcn_mfma_f32_16x16x32_bf16(kf0, qf0, z4, 0, 0, 0);
      s = __builtin_amdgcn_mfma_f32_16x16x32_bf16(kf1, qf1, s, 0, 0, 0);
      zh += __expf(s[0]) + __expf(s[1]) + __expf(s[2]) + __expf(s[3]);
    }
    zh += __shfl_xor(zh, 16); zh += __shfl_xor(zh, 32);
    if (quad == 0) atomicAdd(&zl[h][c], zh);
  }
  __syncthreads();
  if (tid < 128) {
    int h = tid >> 4, q = tid & 15;
    Zpart[(size_t)((b * 64 + qt) * 8 + h) * 64 + kq * 16 + q] = zl[h][q];
  }
}

// ---------------------------------------------------------------------------
// Kernel 4: zpass2 — gate + pair-packed masks. grid (16 = b*4+kq, 64 qt),
// h-outer (low VGPR) -> (512,8). ZERO LDS, ZERO barriers. One uint2 mask
// store per wave (both kt halves of one ktp).
// ---------------------------------------------------------------------------
__global__ __launch_bounds__(512, 8) void zpass2_kernel(
    const unsigned short* __restrict__ Qfrag, const unsigned short* __restrict__ Kfrag,
    const float* __restrict__ Zpart,
    const float* __restrict__ conv_w, const float* __restrict__ conv_b,
    unsigned int* __restrict__ Mfrag) {
  const int b = blockIdx.x >> 2, kq = blockIdx.x & 3;
  const int qt = blockIdx.y;
  const int tid = threadIdx.x, w = tid >> 6, lane = tid & 63;
  const int c = lane & 15;

  f32x4 z4 = {0.f, 0.f, 0.f, 0.f};
  const float cb = conv_b[0];
  const size_t qbase = (size_t)((b * 64 + qt) * 8192) + lane * 8;
  const int kt0 = kq * 16 + w * 2;
  const size_t kb0 = (size_t)((b * 64 + kt0) * 8192) + lane * 8;

  f32x4 zc0 = {cb, cb, cb, cb};
  f32x4 zc1 = zc0;

  for (int h = 0; h < 8; h++) {
    bf16x8 qf0 = *(const bf16x8*)&Qfrag[qbase + h * 1024];
    bf16x8 qf1 = *(const bf16x8*)&Qfrag[qbase + h * 1024 + 512];
    const float* zp = &Zpart[(size_t)((b * 64 + qt) * 8 + h) * 64];
    const float cwz = conv_w[h] / (zp[c] + zp[16 + c] + zp[32 + c] + zp[48 + c]);
    const size_t kba = kb0 + h * 1024;
    bf16x8 ka0 = *(const bf16x8*)&Kfrag[kba];
    bf16x8 ka1 = *(const bf16x8*)&Kfrag[kba + 512];
    bf16x8 kb0f = *(const bf16x8*)&Kfrag[kba + 8192];
    bf16x8 kb1f = *(const bf16x8*)&Kfrag[kba + 8192 + 512];
    f32x4 sa = __builtin_amdgcn_mfma_f32_16x16x32_bf16(ka0, qf0, z4, 0, 0, 0);
    sa = __builtin_amdgcn_mfma_f32_16x16x32_bf16(ka1, qf1, sa, 0, 0, 0);
    f32x4 sb = __builtin_amdgcn_mfma_f32_16x16x32_bf16(kb0f, qf0, z4, 0, 0, 0);
    sb = __builtin_amdgcn_mfma_f32_16x16x32_bf16(kb1f, qf1, sb, 0, 0, 0);
    zc0[0] += cwz * __expf(sa[0]); zc0[1] += cwz * __expf(sa[1]);
    zc0[2] += cwz * __expf(sa[2]); zc0[3] += cwz * __expf(sa[3]);
    zc1[0] += cwz * __expf(sb[0]); zc1[1] += cwz * __expf(sb[1]);
    zc1[2] += cwz * __expf(sb[2]); zc1[3] += cwz * __expf(sb[3]);
  }

  unsigned int p0 = 0, p1 = 0;
#pragma unroll
  for (int r = 0; r < 4; r++) {
    p0 |= ((zc0[r] <= 0.f ? 1u : 0u) | (zc0[r] >= 0.f ? 2u : 0u)) << (8 * r);
    p1 |= ((zc1[r] <= 0.f ? 1u : 0u) | (zc1[r] >= 0.f ? 2u : 0u)) << (8 * r);
  }
  const int ktp = kq * 8 + w;
  uint2 mm; mm.x = p0; mm.y = p1;
  *(uint2*)&Mfrag[(size_t)(b * 64 + qt) * 4096 + (size_t)ktp * 128 + lane * 2] = mm;
}

// ---------------------------------------------------------------------------
// Kernel 5: pv — grid (8 h, 128 = b*32+qb), 256 thr = 4 waves =
// (2 q-tiles x 2 k-halves) -> 4 blocks/CU, 16 waves/CU. Pair-packed K=32
// MFMAs; denominators via ones-row MFMA; phased LDS combine in the epilogue.
// ---------------------------------------------------------------------------
__global__ __launch_bounds__(256, 4) void pv_kernel(
    const unsigned short* __restrict__ Qfrag, const unsigned short* __restrict__ Kfrag,
    const unsigned short* __restrict__ Vfrag,
    const unsigned int* __restrict__ Mfrag, const float* __restrict__ Zpart,
    unsigned short* __restrict__ Tfb, unsigned short* __restrict__ Trb) {
  const int h = blockIdx.x;
  const int b = blockIdx.y >> 5, qb = blockIdx.y & 31;
  const int tid = threadIdx.x, w = tid >> 6, lane = tid & 63;
  const int c = lane & 15, quad = lane >> 4;
  const int qloc = w & 1, kh = w >> 1;
  const int qt = qb * 2 + qloc;

  __shared__ __attribute__((aligned(16))) float red[2][4][256][4];  // 32 KB, reused
  __shared__ float zb[2][2][16];

  f32x4 z4 = {0.f, 0.f, 0.f, 0.f};
  const size_t qbase = (size_t)((b * 64 + qt) * 8192) + h * 1024 + lane * 8;
  bf16x8 qf0 = *(const bf16x8*)&Qfrag[qbase];
  bf16x8 qf1 = *(const bf16x8*)&Qfrag[qbase + 512];
  const float* zpp = &Zpart[(size_t)((b * 64 + qt) * 8 + h) * 64];
  const float invZ = 1.0f / (zpp[c] + zpp[16 + c] + zpp[32 + c] + zpp[48 + c]);
  const size_t mbase = (size_t)(b * 64 + qt) * 4096 + lane * 2;
  const size_t vb0 = (size_t)(b * 8 + h) * 65536 + lane * 8;

  frag_u ones;
  ones.u[0] = 0x3F803F80u; ones.u[1] = 0x3F803F80u;
  ones.u[2] = 0x3F803F80u; ones.u[3] = 0x3F803F80u;

  f32x4 accf[4], accr[4];
#pragma unroll
  for (int i = 0; i < 4; i++) { accf[i] = z4; accr[i] = z4; }
  f32x4 acc_zf = z4, acc_zr = z4;

#pragma unroll 2
  for (int ip = 0; ip < 16; ip++) {
    const int ktp = kh * 16 + ip;
    const int kta = ktp * 2, ktb = kta + 1;
    const size_t kba = (size_t)((b * 64 + kta) * 8192) + h * 1024 + lane * 8;
    const size_t kbb = (size_t)((b * 64 + ktb) * 8192) + h * 1024 + lane * 8;
    bf16x8 ka0 = *(const bf16x8*)&Kfrag[kba];
    bf16x8 ka1 = *(const bf16x8*)&Kfrag[kba + 512];
    bf16x8 kb0 = *(const bf16x8*)&Kfrag[kbb];
    bf16x8 kb1 = *(const bf16x8*)&Kfrag[kbb + 512];
    f32x4 sa = __builtin_amdgcn_mfma_f32_16x16x32_bf16(ka0, qf0, z4, 0, 0, 0);
    sa = __builtin_amdgcn_mfma_f32_16x16x32_bf16(ka1, qf1, sa, 0, 0, 0);
    f32x4 sb = __builtin_amdgcn_mfma_f32_16x16x32_bf16(kb0, qf0, z4, 0, 0, 0);
    sb = __builtin_amdgcn_mfma_f32_16x16x32_bf16(kb1, qf1, sb, 0, 0, 0);
    const uint2 mp = *(const uint2*)&Mfrag[mbase + (size_t)ktp * 128];
    float ea[4], eb[4];
#pragma unroll
    for (int r = 0; r < 4; r++) {
      ea[r] = __expf(__expf(sa[r]) * invZ);
      eb[r] = __expf(__expf(sb[r]) * invZ);
    }
    frag_u pF, pR;
    pF.u[0] = pack_bf16((mp.x & 0x1u) ? ea[0] : 1.f, (mp.x & 0x100u) ? ea[1] : 1.f);
    pF.u[1] = pack_bf16((mp.x & 0x10000u) ? ea[2] : 1.f, (mp.x & 0x1000000u) ? ea[3] : 1.f);
    pF.u[2] = pack_bf16((mp.y & 0x1u) ? eb[0] : 1.f, (mp.y & 0x100u) ? eb[1] : 1.f);
    pF.u[3] = pack_bf16((mp.y & 0x10000u) ? eb[2] : 1.f, (mp.y & 0x1000000u) ? eb[3] : 1.f);
    pR.u[0] = pack_bf16((mp.x & 0x2u) ? ea[0] : 1.f, (mp.x & 0x200u) ? ea[1] : 1.f);
    pR.u[1] = pack_bf16((mp.x & 0x20000u) ? ea[2] : 1.f, (mp.x & 0x2000000u) ? ea[3] : 1.f);
    pR.u[2] = pack_bf16((mp.y & 0x2u) ? eb[0] : 1.f, (mp.y & 0x200u) ? eb[1] : 1.f);
    pR.u[3] = pack_bf16((mp.y & 0x20000u) ? eb[2] : 1.f, (mp.y & 0x2000000u) ? eb[3] : 1.f);
    acc_zf = __builtin_amdgcn_mfma_f32_16x16x32_bf16(ones.v, pF.v, acc_zf, 0, 0, 0);
    acc_zr = __builtin_amdgcn_mfma_f32_16x16x32_bf16(ones.v, pR.v, acc_zr, 0, 0, 0);
#pragma unroll
    for (int dm = 0; dm < 4; dm++) {
      bf16x8 vf = *(const bf16x8*)&Vfrag[vb0 + (size_t)(ktp * 4 + dm) * 512];
      accf[dm] = __builtin_amdgcn_mfma_f32_16x16x32_bf16(vf, pF.v, accf[dm], 0, 0, 0);
      accr[dm] = __builtin_amdgcn_mfma_f32_16x16x32_bf16(vf, pR.v, accr[dm], 0, 0, 0);
    }
  }

  // ---- cross-kh combine (phased through the 32KB red buffer) ----
  if (kh == 1) {
#pragma unroll
    for (int dm = 0; dm < 4; dm++) *(f32x4*)red[qloc][dm][lane] = accf[dm];
    if (lane < 16) { zb[qloc][0][lane] = acc_zf[0]; zb[qloc][1][lane] = acc_zr[0]; }
  }
  __syncthreads();
  if (kh == 0) {
#pragma unroll
    for (int dm = 0; dm < 4; dm++) accf[dm] += *(f32x4*)red[qloc][dm][lane];
  }
  __syncthreads();
  if (kh == 1) {
#pragma unroll
    for (int dm = 0; dm < 4; dm++) *(f32x4*)red[qloc][dm][lane] = accr[dm];
  }
  __syncthreads();
  uint2 outf[4], outr[4];
  if (kh == 0) {
#pragma unroll
    for (int dm = 0; dm < 4; dm++) accr[dm] += *(f32x4*)red[qloc][dm][lane];
    const float zf = acc_zf[0] + zb[qloc][0][c];
    const float zr = acc_zr[0] + zb[qloc][1][c];
    const float izf = 1.0f / zf, izr = 1.0f / zr;
#pragma unroll
    for (int dm = 0; dm < 4; dm++) {
      outf[dm].x = pack_bf16(accf[dm][0] * izf, accf[dm][1] * izf);
      outf[dm].y = pack_bf16(accf[dm][2] * izf, accf[dm][3] * izf);
      outr[dm].x = pack_bf16(accr[dm][0] * izr, accr[dm][1] * izr);
      outr[dm].y = pack_bf16(accr[dm][2] * izr, accr[dm][3] * izr);
    }
  }
  __syncthreads();
  unsigned short* ts = (unsigned short*)red;  // 64 rows x 72 = 9.2 KB < 32 KB
  if (kh == 0) {
    const int qrow = qloc * 16 + c;
#pragma unroll
    for (int dm = 0; dm < 4; dm++) {
      *(uint2*)&ts[qrow * 72 + dm * 16 + quad * 4] = outf[dm];
      *(uint2*)&ts[(32 + qrow) * 72 + dm * 16 + quad * 4] = outr[dm];
    }
  }
  __syncthreads();
  {
    const int row = tid >> 3, seg = tid & 7;
    const size_t g = (size_t)(b * 1024 + qb * 32 + row) * 512 + h * 64 + seg * 8;
    *(uint4*)&Tfb[g] = *(uint4*)&ts[row * 72 + seg * 8];
    *(uint4*)&Trb[g] = *(uint4*)&ts[(32 + row) * 72 + seg * 8];
  }
}

// ---------------------------------------------------------------------------
// Kernel 6: final — LDS-staged fused 4-GEMM + gate combine.
// grid (8 nb, 128 mt32): 32m x 64n tiles, LDS 40 KB -> 4 blocks/CU.
// ---------------------------------------------------------------------------
__global__ __launch_bounds__(256, 4) void final_kernel(
    const unsigned short* __restrict__ Tfb, const unsigned short* __restrict__ Trb,
    const unsigned short* __restrict__ wfh, const unsigned short* __restrict__ wfg,
    const unsigned short* __restrict__ wrh, const unsigned short* __restrict__ wrg,
    const float* __restrict__ bfh, const float* __restrict__ bfg,
    const float* __restrict__ brh, const float* __restrict__ brg,
    float* __restrict__ out) {
  __shared__ unsigned short Atf[32 * 64];
  __shared__ unsigned short Atr[32 * 64];
  __shared__ unsigned short Bfh[64 * 64];
  __shared__ unsigned short Bfg[64 * 64];
  __shared__ unsigned short Brh[64 * 64];
  __shared__ unsigned short Brg[64 * 64];
  const int m0 = blockIdx.y * 32, n0 = blockIdx.x * 64;
  const int tid = threadIdx.x, w = tid >> 6, lane = tid & 63;
  const int c = lane & 15, quad = lane >> 4;
  const int wm = w & 1, wn = w >> 1;
  const int rsel = lane >> 3, csel = lane & 7;
  const int sc = csel ^ rsel;
  // A tiles: wave stages 8 rows (1 gload16); B tiles: 16 rows (2 gload16).
  const char* Agf = (const char*)Tfb + (size_t)(m0 + w * 8 + rsel) * 1024 + sc * 16;
  const char* Agr = (const char*)Trb + (size_t)(m0 + w * 8 + rsel) * 1024 + sc * 16;
  const char* Bg0 = (const char*)wfh + (size_t)(n0 + w * 16 + rsel) * 1024 + sc * 16;
  const char* Bg1 = (const char*)wfg + (size_t)(n0 + w * 16 + rsel) * 1024 + sc * 16;
  const char* Bg2 = (const char*)wrh + (size_t)(n0 + w * 16 + rsel) * 1024 + sc * 16;
  const char* Bg3 = (const char*)wrg + (size_t)(n0 + w * 16 + rsel) * 1024 + sc * 16;
  unsigned short* lAf = &Atf[w * 512];
  unsigned short* lAr = &Atr[w * 512];
  unsigned short* l0 = &Bfh[w * 1024];
  unsigned short* l1 = &Bfg[w * 1024];
  unsigned short* l2 = &Brh[w * 1024];
  unsigned short* l3 = &Brg[w * 1024];

  f32x4 acc[4][2];  // [mat][nt]
  f32x4 z4 = {0.f, 0.f, 0.f, 0.f};
#pragma unroll
  for (int o = 0; o < 4; o++)
#pragma unroll
    for (int j = 0; j < 2; j++) acc[o][j] = z4;

  for (int ks = 0; ks < 8; ks++) {
    if (ks) __syncthreads();
    const int kb = ks * 128;
    gload16(Agf + kb, lAf);
    gload16(Agr + kb, lAr);
    gload16(Bg0 + kb, l0);   gload16(Bg0 + kb + 8192, l0 + 512);
    gload16(Bg1 + kb, l1);   gload16(Bg1 + kb + 8192, l1 + 512);
    gload16(Bg2 + kb, l2);   gload16(Bg2 + kb + 8192, l2 + 512);
    gload16(Bg3 + kb, l3);   gload16(Bg3 + kb + 8192, l3 + 512);
    __syncthreads();
#pragma unroll
    for (int ch = 0; ch < 2; ch++) {
      const int cq = ch * 4 + quad;
      bf16x8 af = lds_frag(Atf, wm * 16 + c, cq);
      bf16x8 ar = lds_frag(Atr, wm * 16 + c, cq);
#pragma unroll
      for (int nt = 0; nt < 2; nt++) {
        const int rb = wn * 32 + nt * 16 + c;
        bf16x8 f0 = lds_frag(Bfh, rb, cq);
        bf16x8 f1 = lds_frag(Bfg, rb, cq);
        bf16x8 f2 = lds_frag(Brh, rb, cq);
        bf16x8 f3 = lds_frag(Brg, rb, cq);
        acc[0][nt] = __builtin_amdgcn_mfma_f32_16x16x32_bf16(af, f0, acc[0][nt], 0, 0, 0);
        acc[1][nt] = __builtin_amdgcn_mfma_f32_16x16x32_bf16(af, f1, acc[1][nt], 0, 0, 0);
        acc[2][nt] = __builtin_amdgcn_mfma_f32_16x16x32_bf16(ar, f2, acc[2][nt], 0, 0, 0);
        acc[3][nt] = __builtin_amdgcn_mfma_f32_16x16x32_bf16(ar, f3, acc[3][nt], 0, 0, 0);
      }
    }
  }

#pragma unroll
  for (int nt = 0; nt < 2; nt++) {
    int n = n0 + wn * 32 + nt * 16 + c;
    float b0 = bfh[n], b1 = bfg[n], b2 = brh[n], b3 = brg[n];
    int t0 = m0 + wm * 16 + quad * 4;
#pragma unroll
    for (int r = 0; r < 4; r++) {
      int t = t0 + r;
      float Ff = acc[0][nt][r] + b0;
      float Gf = 1.0f / (1.0f + __expf(-(acc[1][nt][r] + b1)));
      float Fr = acc[2][nt][r] + b2;
      float Gr = 1.0f / (1.0f + __expf(-(acc[3][nt][r] + b3)));
      float ef = __expf(Gf), er = __expf(Gr);
      out[(size_t)t * 512 + n] = (Ff * ef + Fr * er) / (ef + er);
    }
  }
}

// ---------------------------------------------------------------------------
// Launch. Workspace (bytes):
//   0: xb 4MB | 4: Qfrag 4MB | 8: Kfrag 4MB | 12: Vfrag 4MB
//   16: Tfb 4MB | 20: Trb 4MB | 24: wt 3.5MB | 28: Mfrag 4MB | 32: Zpart 512KB
// ---------------------------------------------------------------------------
extern "C" void kernel_launch(void* const* d_in, const int* in_sizes, int n_in,
                              void* d_out, int out_size, void* d_ws, size_t ws_size,
                              hipStream_t stream) {
  const float* x   = (const float*)d_in[0];
  const float* Wq  = (const float*)d_in[1];
  const float* bq  = (const float*)d_in[2];
  const float* Wk  = (const float*)d_in[3];
  const float* bk  = (const float*)d_in[4];
  const float* Wv  = (const float*)d_in[5];
  const float* bv  = (const float*)d_in[6];
  const float* cw  = (const float*)d_in[7];
  const float* cb  = (const float*)d_in[8];
  const float* Wfh = (const float*)d_in[9];
  const float* bfh = (const float*)d_in[10];
  const float* Wfg = (const float*)d_in[11];
  const float* bfg = (const float*)d_in[12];
  const float* Wrh = (const float*)d_in[13];
  const float* brh = (const float*)d_in[14];
  const float* Wrg = (const float*)d_in[15];
  const float* brg = (const float*)d_in[16];

  char* ws = (char*)d_ws;
  const size_t MB = 1024 * 1024;
  unsigned short* xb    = (unsigned short*)(ws + 0 * MB);
  unsigned short* Qfrag = (unsigned short*)(ws + 4 * MB);
  unsigned short* Kfrag = (unsigned short*)(ws + 8 * MB);
  unsigned short* Vfrag = (unsigned short*)(ws + 12 * MB);
  unsigned short* Tfb   = (unsigned short*)(ws + 16 * MB);
  unsigned short* Trb   = (unsigned short*)(ws + 20 * MB);
  unsigned short* wt    = (unsigned short*)(ws + 24 * MB);
  unsigned int*   Mfrag = (unsigned int*)(ws + 28 * MB);
  float*          Zpart = (float*)(ws + 32 * MB);
  const size_t WSZ = 512 * 512;

  prep_kernel<<<512, 256, 0, stream>>>(x, Wq, Wk, Wv, Wfh, Wfg, Wrh, Wrg, xb, wt);
  qkv_kernel<<<dim3(8, 64), 256, 0, stream>>>(xb, wt + 0 * WSZ, wt + 1 * WSZ, wt + 2 * WSZ,
                                              bq, bk, bv, Qfrag, Kfrag, Vfrag);
  zpass1_kernel<<<dim3(16, 64), 512, 0, stream>>>(Qfrag, Kfrag, Zpart);
  zpass2_kernel<<<dim3(16, 64), 512, 0, stream>>>(Qfrag, Kfrag, Zpart, cw, cb, Mfrag);
  pv_kernel<<<dim3(8, 128), 256, 0, stream>>>(Qfrag, Kfrag, Vfrag, Mfrag, Zpart, Tfb, Trb);
  final_kernel<<<dim3(8, 128), 256, 0, stream>>>(Tfb, Trb, wt + 3 * WSZ, wt + 4 * WSZ,
                                                 wt + 5 * WSZ, wt + 6 * WSZ,
                                                 bfh, bfg, brh, brg, (float*)d_out);
}